// Round 4
// baseline (525.922 us; speedup 1.0000x reference)
//
#include <hip/hip_runtime.h>
#include <hip/hip_fp16.h>
#include <stdint.h>

#define G      128
#define OUTW   128
#define RNUM   6

typedef unsigned short us;
typedef _Float16 f16x8 __attribute__((ext_vector_type(8)));
typedef float    f32x4 __attribute__((ext_vector_type(4)));

__device__ inline float h2f(us u) { __half h; *(us*)&h = u; return __half2float(h); }
__device__ inline us f2h(float f) { __half h = __float2half(f); return *(us*)&h; }

union FragU { f16x8 v; ushort4 u[2]; };

// ---------------- K1: per-(dst,rel) segment counts ----------------
__global__ void count_kernel(const int* __restrict__ ei, const int* __restrict__ et,
                             int* __restrict__ segcnt, int N, int E) {
    int e = blockIdx.x * blockDim.x + threadIdx.x;
    if (e >= E) return;
    int dst = ei[E + e];
    int r   = et[e];
    atomicAdd(&segcnt[dst * RNUM + r], 1);
}

// ---------------- scan: 3-phase over n = N*RNUM segments ----------------
__global__ __launch_bounds__(256)
void scan_part(const int* __restrict__ cnt, int* __restrict__ bsum, int n) {
    __shared__ int s[256];
    int base = blockIdx.x * 1024, t = threadIdx.x;
    int v = 0;
    for (int j = 0; j < 4; ++j) { int idx = base + j * 256 + t; if (idx < n) v += cnt[idx]; }
    s[t] = v; __syncthreads();
    for (int off = 128; off; off >>= 1) { if (t < off) s[t] += s[t + off]; __syncthreads(); }
    if (!t) bsum[blockIdx.x] = s[0];
}

__global__ __launch_bounds__(512)
void scan_top(const int* __restrict__ bsum, int* __restrict__ boff,
              int* __restrict__ segptr, int nb, int n) {
    __shared__ int s[512];
    int t = threadIdx.x;
    int v = (t < nb) ? bsum[t] : 0;
    s[t] = v;
    __syncthreads();
    for (int off = 1; off < 512; off <<= 1) {
        int y = (t >= off) ? s[t - off] : 0;
        __syncthreads();
        s[t] += y;
        __syncthreads();
    }
    if (t < nb) boff[t + 1] = s[t];
    if (!t) boff[0] = 0;
    if (t == nb - 1) segptr[n] = s[t];     // grand total = E
}

__global__ __launch_bounds__(256)
void scan_apply(const int* __restrict__ cnt, const int* __restrict__ boff,
                int* __restrict__ segptr, int* __restrict__ cursor, int n) {
    __shared__ int L[1024];
    __shared__ int SS[256];
    int base = blockIdx.x * 1024, t = threadIdx.x;
    for (int j = 0; j < 4; ++j) { int idx = base + j * 256 + t; L[j * 256 + t] = (idx < n) ? cnt[idx] : 0; }
    __syncthreads();
    int s0 = L[t*4] + L[t*4+1] + L[t*4+2] + L[t*4+3];
    SS[t] = s0; __syncthreads();
    for (int off = 1; off < 256; off <<= 1) {
        int y = (t >= off) ? SS[t - off] : 0;
        __syncthreads();
        SS[t] += y;
        __syncthreads();
    }
    int e0 = (t ? SS[t - 1] : 0) + boff[blockIdx.x];
    int4 ov;
    int a;
    a = L[t*4+0]; ov.x = e0; e0 += a;
    a = L[t*4+1]; ov.y = e0; e0 += a;
    a = L[t*4+2]; ov.z = e0; e0 += a;
    a = L[t*4+3]; ov.w = e0; e0 += a;
    int idx0 = base + t * 4;
    if (idx0 + 3 < n) {
        *(int4*)(segptr + idx0) = ov;
        *(int4*)(cursor + idx0) = ov;
    } else {
        int vals[4] = {ov.x, ov.y, ov.z, ov.w};
        for (int k = 0; k < 4; ++k)
            if (idx0 + k < n) { segptr[idx0 + k] = vals[k]; cursor[idx0 + k] = vals[k]; }
    }
}

// ---------------- K3: scatter edges into composite CSR ----------------
__global__ void scatter_kernel(const int* __restrict__ ei, const int* __restrict__ et,
                               int* __restrict__ cursor, unsigned* __restrict__ esrc,
                               int N, int E) {
    int e = blockIdx.x * blockDim.x + threadIdx.x;
    if (e >= E) return;
    int src = ei[e];
    int dst = ei[E + e];
    int r   = et[e];
    int pos = atomicAdd(&cursor[dst * RNUM + r], 1);
    esrc[pos] = (unsigned)src;
}

// ---------------- K: fp32 -> fp16 copy of x ----------------
__global__ void xhalf_kernel(const float* __restrict__ x, us* __restrict__ xh, int total8) {
    int i = blockIdx.x * blockDim.x + threadIdx.x;
    if (i >= total8) return;
    float4 a = ((const float4*)x)[2*i];
    float4 b = ((const float4*)x)[2*i+1];
    ushort4 u0 = { f2h(a.x), f2h(a.y), f2h(a.z), f2h(a.w) };
    ushort4 u1 = { f2h(b.x), f2h(b.y), f2h(b.z), f2h(b.w) };
    ((ushort4*)xh)[2*i]   = u0;
    ((ushort4*)xh)[2*i+1] = u1;
}

// ---------------- weight prep: fp16 fragment-layout conversions ----------------
// Btr[kq][n][i] = Wcat[4kq+i][n], Wcat = [Wrel(768) ; Wroot(128)], kq<224, n<128
__global__ __launch_bounds__(256)
void wconv_rgcn(const float* __restrict__ Wrel, const float* __restrict__ Wroot,
                ushort4* __restrict__ Btr) {
    int idx = blockIdx.x * 256 + threadIdx.x;
    if (idx >= 224 * 128) return;
    int kq = idx >> 7, n = idx & 127;
    ushort4 o;
    us* op = (us*)&o;
#pragma unroll
    for (int i = 0; i < 4; ++i) {
        int k = 4 * kq + i;
        float v = (k < 768) ? Wrel[(size_t)k * 128 + n] : Wroot[(size_t)(k - 768) * 128 + n];
        op[i] = f2h(v);
    }
    Btr[idx] = o;
}

// Btq[kq][n][i] = Wsel(n/128)[4kq+i][n%128], kq<32, n<512 (q|k|v|s)
__global__ __launch_bounds__(256)
void wconv_qkvs(const float* __restrict__ Wq, const float* __restrict__ Wk,
                const float* __restrict__ Wv, const float* __restrict__ Ws,
                ushort4* __restrict__ Btq) {
    int idx = blockIdx.x * 256 + threadIdx.x;
    if (idx >= 32 * 512) return;
    int kq = idx >> 9, n = idx & 511;
    int quad = n >> 7, nl = n & 127;
    const float* W = (quad == 0) ? Wq : (quad == 1) ? Wk : (quad == 2) ? Wv : Ws;
    ushort4 o;
    us* op = (us*)&o;
#pragma unroll
    for (int i = 0; i < 4; ++i) {
        int k = 4 * kq + i;
        op[i] = f2h(W[(size_t)k * 128 + nl]);
    }
    Btq[idx] = o;
}

// ---------------- K4: FUSED aggregation + RGCN GEMM ----------------
// 64 rows/block, 256 threads. For each of 7 K=128 chunks (6 relation means + root),
// gather the chunk straight into the LDS A-panel (fragment layout), then MFMA.
__global__ __launch_bounds__(256)
void rgcn_fused(const us* __restrict__ xh, const int* __restrict__ segptr,
                const unsigned* __restrict__ esrc, const ushort4* __restrict__ Btr,
                const float* __restrict__ brg, us* __restrict__ xrh, int N) {
    __shared__ ushort4 Ald[64][33];      // [row][kq], +1 pad: ~16.9 KB
    const int tid = threadIdx.x;
    const int w = tid >> 6, l = tid & 63;
    const int lh = l >> 4, lm = l & 15;
    const int base = blockIdx.x * 64;
    const int arow = w * 16 + lm;

    f32x4 acc[8];
#pragma unroll
    for (int ct = 0; ct < 8; ++ct) {
        float b = brg[ct * 16 + lm];
        acc[ct] = (f32x4){b, b, b, b};
    }

    for (int ch = 0; ch < 7; ++ch) {
        __syncthreads();                 // previous chunk's MFMA reads complete
        // ---- build this chunk's 16 rows owned by wave w ----
        for (int j = 0; j < 16; ++j) {
            const int row = w * 16 + j;
            const int i = base + row;
            float2 a = {0.f, 0.f};
            if (i < N) {
                if (ch < 6) {
                    int s0 = __builtin_amdgcn_readfirstlane(segptr[i * RNUM + ch]);
                    int s1 = __builtin_amdgcn_readfirstlane(segptr[i * RNUM + ch + 1]);
                    int e = s0;
                    for (; e + 4 <= s1; e += 4) {
                        unsigned q0 = __builtin_amdgcn_readfirstlane(esrc[e]);
                        unsigned q1 = __builtin_amdgcn_readfirstlane(esrc[e + 1]);
                        unsigned q2 = __builtin_amdgcn_readfirstlane(esrc[e + 2]);
                        unsigned q3 = __builtin_amdgcn_readfirstlane(esrc[e + 3]);
                        ushort2 u0 = *(const ushort2*)(xh + (size_t)q0 * G + 2 * l);
                        ushort2 u1 = *(const ushort2*)(xh + (size_t)q1 * G + 2 * l);
                        ushort2 u2 = *(const ushort2*)(xh + (size_t)q2 * G + 2 * l);
                        ushort2 u3 = *(const ushort2*)(xh + (size_t)q3 * G + 2 * l);
                        a.x += (h2f(u0.x) + h2f(u1.x)) + (h2f(u2.x) + h2f(u3.x));
                        a.y += (h2f(u0.y) + h2f(u1.y)) + (h2f(u2.y) + h2f(u3.y));
                    }
                    for (; e < s1; ++e) {
                        unsigned q0 = __builtin_amdgcn_readfirstlane(esrc[e]);
                        ushort2 u0 = *(const ushort2*)(xh + (size_t)q0 * G + 2 * l);
                        a.x += h2f(u0.x);
                        a.y += h2f(u0.y);
                    }
                    float sc = 1.f / fmaxf((float)(s1 - s0), 1.f);
                    a.x *= sc; a.y *= sc;
                } else {
                    ushort2 u = *(const ushort2*)(xh + (size_t)i * G + 2 * l);
                    a.x = h2f(u.x); a.y = h2f(u.y);
                }
            }
            ushort2 t = { f2h(a.x), f2h(a.y) };
            *((ushort2*)&Ald[row][l >> 1] + (l & 1)) = t;
        }
        __syncthreads();
        // ---- MFMA over this K=128 chunk ----
#pragma unroll
        for (int s = 0; s < 4; ++s) {
            FragU af;
            const int kql = s * 8 + lh;
            af.u[0] = Ald[arow][kql];
            af.u[1] = Ald[arow][kql + 4];
            const int kqg = ch * 32 + kql;
            const ushort4* B0 = Btr + (size_t)kqg * 128;
            const ushort4* B1 = Btr + (size_t)(kqg + 4) * 128;
#pragma unroll
            for (int ct = 0; ct < 8; ++ct) {
                FragU bf;
                bf.u[0] = B0[ct * 16 + lm];
                bf.u[1] = B1[ct * 16 + lm];
                acc[ct] = __builtin_amdgcn_mfma_f32_16x16x32_f16(af.v, bf.v, acc[ct], 0, 0, 0);
            }
        }
    }

    // store: D row = w*16 + 4*lh + i, col = ct*16 + lm
#pragma unroll
    for (int ct = 0; ct < 8; ++ct) {
#pragma unroll
        for (int i = 0; i < 4; ++i) {
            int r = base + w * 16 + 4 * lh + i;
            if (r < N) xrh[(size_t)r * 128 + ct * 16 + lm] = f2h(acc[ct][i]);
        }
    }
}

// ---------------- K6: q|k|v|skip via MFMA ----------------
__global__ __launch_bounds__(256)
void qkvs_mfma(const us* __restrict__ xrh, const ushort4* __restrict__ Btq,
               const float* __restrict__ bq, const float* __restrict__ bk,
               const float* __restrict__ bv, const float* __restrict__ bs,
               float* __restrict__ qs, us* __restrict__ kvh, int N) {
    __shared__ ushort4 Ald[32 * 16];     // [kq][m], 4 KB
    const int tid = threadIdx.x;
    const int w = tid >> 6, l = tid & 63;
    const int lh = l >> 4, lm = l & 15;
    const int base = blockIdx.x * 16;

    {   // stage 16 rows x 128 k : 1 int4 per thread
        int row = tid >> 4, k0 = (tid & 15) * 8;
        int gi = base + row;
        int4 d0 = {0,0,0,0};
        if (gi < N) d0 = *(const int4*)(xrh + (size_t)gi * 128 + k0);
        int kqb = k0 >> 2;
        Ald[(kqb + 0) * 16 + row] = ((ushort4*)&d0)[0];
        Ald[(kqb + 1) * 16 + row] = ((ushort4*)&d0)[1];
    }
    __syncthreads();

    const float* bias = (w == 0) ? bq : (w == 1) ? bk : (w == 2) ? bv : bs;
    f32x4 acc[8];
#pragma unroll
    for (int ct = 0; ct < 8; ++ct) {
        float b = bias[ct * 16 + lm];
        acc[ct] = (f32x4){b, b, b, b};
    }

#pragma unroll
    for (int s = 0; s < 4; ++s) {
        FragU af;
        int kq = s * 8 + lh;
        af.u[0] = Ald[kq * 16 + lm];
        af.u[1] = Ald[(kq + 4) * 16 + lm];
        const ushort4* B0 = Btq + (size_t)kq * 512 + w * 128;
        const ushort4* B1 = Btq + (size_t)(kq + 4) * 512 + w * 128;
#pragma unroll
        for (int ct = 0; ct < 8; ++ct) {
            FragU bf;
            bf.u[0] = B0[ct * 16 + lm];
            bf.u[1] = B1[ct * 16 + lm];
            acc[ct] = __builtin_amdgcn_mfma_f32_16x16x32_f16(af.v, bf.v, acc[ct], 0, 0, 0);
        }
    }

    if (w == 0 || w == 3) {
        int off = (w == 0) ? 0 : 128;
#pragma unroll
        for (int ct = 0; ct < 8; ++ct)
#pragma unroll
            for (int i = 0; i < 4; ++i) {
                int r = base + 4 * lh + i;
                if (r < N) qs[(size_t)r * 256 + off + ct * 16 + lm] = acc[ct][i];
            }
    } else {
        int off = (w == 1) ? 0 : 2;      // k or v interleave slot
#pragma unroll
        for (int ct = 0; ct < 8; ++ct)
#pragma unroll
            for (int i = 0; i < 4; ++i) {
                int r = base + 4 * lh + i;
                int col = ct * 16 + lm;
                if (r < N) kvh[(size_t)r * 256 + (col >> 1) * 4 + (col & 1) + off] = f2h(acc[ct][i]);
            }
    }
}

// ---------------- K7: attention (wave per node, 4-edge batched online softmax) ----------------
__global__ __launch_bounds__(256)
void attn_kernel(const float* __restrict__ qs, const us* __restrict__ kvh,
                 const int* __restrict__ segptr, const unsigned* __restrict__ esrc,
                 float* __restrict__ out, int N) {
    const int wv = threadIdx.x >> 6, l = threadIdx.x & 63;
    const int i = blockIdx.x * 4 + wv;
    if (i >= N) return;
    const float QS = 0.17677669529663687f;   // 1/sqrt(32)

    float2 q2 = *(const float2*)(qs + (size_t)i * 256 + 2*l);
    q2.x *= QS; q2.y *= QS;

    float m = -INFINITY, den = 0.f;
    float2 acc = {0.f, 0.f};
    const int e0 = segptr[(size_t)i * RNUM], e1 = segptr[(size_t)i * RNUM + RNUM];

#define KVLOAD(P) (*(const ushort4*)(kvh + (size_t)(P) * 256 + 4*l))
#define SCORE(U, S) { \
    float s_ = q2.x * h2f((U).x) + q2.y * h2f((U).y); \
    s_ += __shfl_xor(s_, 1, 16); s_ += __shfl_xor(s_, 2, 16); \
    s_ += __shfl_xor(s_, 4, 16); s_ += __shfl_xor(s_, 8, 16); \
    S = s_; }

    for (int base = e0; base < e1; base += 64) {
        const int nc = min(64, e1 - base);
        unsigned pv = 0;
        if (base + l < e1) pv = esrc[base + l];
        int j = 0;
        for (; j + 4 <= nc; j += 4) {
            unsigned p0 = (unsigned)__shfl((int)pv, j+0);
            unsigned p1 = (unsigned)__shfl((int)pv, j+1);
            unsigned p2 = (unsigned)__shfl((int)pv, j+2);
            unsigned p3 = (unsigned)__shfl((int)pv, j+3);
            ushort4 k0 = KVLOAD(p0), k1 = KVLOAD(p1), k2 = KVLOAD(p2), k3 = KVLOAD(p3);
            float s0, s1, s2, s3;
            SCORE(k0, s0); SCORE(k1, s1); SCORE(k2, s2); SCORE(k3, s3);
            float mx = fmaxf(fmaxf(fmaxf(s0, s1), fmaxf(s2, s3)), m);
            float rs = __expf(m - mx);
            float p0e = __expf(s0 - mx), p1e = __expf(s1 - mx);
            float p2e = __expf(s2 - mx), p3e = __expf(s3 - mx);
            den = den * rs + ((p0e + p1e) + (p2e + p3e));
            acc.x = acc.x * rs + p0e*h2f(k0.z) + p1e*h2f(k1.z) + p2e*h2f(k2.z) + p3e*h2f(k3.z);
            acc.y = acc.y * rs + p0e*h2f(k0.w) + p1e*h2f(k1.w) + p2e*h2f(k2.w) + p3e*h2f(k3.w);
            m = mx;
        }
        for (; j < nc; ++j) {
            unsigned p0 = (unsigned)__shfl((int)pv, j);
            ushort4 k0 = KVLOAD(p0);
            float s0; SCORE(k0, s0);
            float mx = fmaxf(m, s0);
            float rs = __expf(m - mx);
            float pe = __expf(s0 - mx);
            den = den * rs + pe;
            acc.x = acc.x * rs + pe * h2f(k0.z);
            acc.y = acc.y * rs + pe * h2f(k0.w);
            m = mx;
        }
    }
#undef SCORE
#undef KVLOAD

    float inv = 1.f / (den + 1e-16f);
    float2 sk = *(const float2*)(qs + (size_t)i * 256 + 128 + 2*l);
    float2 o = { acc.x * inv + sk.x, acc.y * inv + sk.y };
    *(float2*)(out + (size_t)i * OUTW + 2*l) = o;
}

// ---------------- K8: BN column reduction ----------------
__global__ __launch_bounds__(256)
void bnreduce_kernel(const float* __restrict__ out, float* __restrict__ bnS,
                     float* __restrict__ bnQ, int N) {
    __shared__ float S[256], Q[256];
    const int tid = threadIdx.x;
    const int col = tid & 127, half = tid >> 7;
    float s = 0.f, q = 0.f;
    for (int r = blockIdx.x * 2 + half; r < N; r += gridDim.x * 2) {
        float v = out[(size_t)r * OUTW + col];
        s += v; q += v * v;
    }
    S[tid] = s; Q[tid] = q;
    __syncthreads();
    if (tid < 128) {
        atomicAdd(&bnS[tid], S[tid] + S[tid + 128]);
        atomicAdd(&bnQ[tid], Q[tid] + Q[tid + 128]);
    }
}

// ---------------- K9: BN stats -> per-column affine A,B ----------------
__global__ void bnstats_kernel(const float* __restrict__ bnS, const float* __restrict__ bnQ,
                               const float* __restrict__ gamma, const float* __restrict__ beta,
                               float* __restrict__ bnA, float* __restrict__ bnB, int N) {
    int c = threadIdx.x;
    if (c >= 128) return;
    float fN  = (float)N;
    float mu  = bnS[c] / fN;
    float var = bnQ[c] / fN - mu * mu;
    float rv  = rsqrtf(var + 1e-5f);
    float A   = rv * gamma[c];
    bnA[c] = A;
    bnB[c] = beta[c] - mu * A;
}

// ---------------- K10: BN apply + LeakyReLU (in-place) ----------------
__global__ void apply_kernel(float* __restrict__ out, const float* __restrict__ bnA,
                             const float* __restrict__ bnB, int total4) {
    int idx4 = blockIdx.x * blockDim.x + threadIdx.x;
    if (idx4 >= total4) return;
    float4 v = ((const float4*)out)[idx4];
    int c0 = (idx4 * 4) & 127;
    float y;
    y = bnA[c0    ] * v.x + bnB[c0    ]; v.x = (y > 0.f) ? y : 0.01f * y;
    y = bnA[c0 + 1] * v.y + bnB[c0 + 1]; v.y = (y > 0.f) ? y : 0.01f * y;
    y = bnA[c0 + 2] * v.z + bnB[c0 + 2]; v.z = (y > 0.f) ? y : 0.01f * y;
    y = bnA[c0 + 3] * v.w + bnB[c0 + 3]; v.w = (y > 0.f) ? y : 0.01f * y;
    ((float4*)out)[idx4] = v;
}

// ---------------- launch ----------------
static inline char* alignp(char* p) {
    return (char*)(((uintptr_t)p + 255) & ~(uintptr_t)255);
}

extern "C" void kernel_launch(void* const* d_in, const int* in_sizes, int n_in,
                              void* d_out, int out_size, void* d_ws, size_t ws_size,
                              hipStream_t stream) {
    const float* x     = (const float*)d_in[0];
    const int*   ei    = (const int*)  d_in[2];
    const int*   et    = (const int*)  d_in[3];
    const float* Wrel  = (const float*)d_in[4];
    const float* Wroot = (const float*)d_in[5];
    const float* brg   = (const float*)d_in[6];
    const float* Wq    = (const float*)d_in[7];
    const float* bq    = (const float*)d_in[8];
    const float* Wk    = (const float*)d_in[9];
    const float* bk    = (const float*)d_in[10];
    const float* Wv    = (const float*)d_in[11];
    const float* bv    = (const float*)d_in[12];
    const float* Wsk   = (const float*)d_in[13];
    const float* bsk   = (const float*)d_in[14];
    const float* gamma = (const float*)d_in[15];
    const float* beta  = (const float*)d_in[16];
    float* out = (float*)d_out;

    const int N = in_sizes[0] / G;
    const int E = in_sizes[3];
    const int NSEG = N * RNUM;
    const int NB_SCAN = (NSEG + 1023) / 1024;   // <= 512

    // ---- workspace carve ----
    char* w = (char*)d_ws;
    int* segcnt = (int*)w;           w += (size_t)NSEG * 4;
    float* bnS = (float*)w;          w += 128 * 4;
    float* bnQ = (float*)w;          w += 128 * 4;
    float* bnA = (float*)w;          w += 128 * 4;
    float* bnB = (float*)w;          w += 128 * 4;
    size_t zero_bytes = (size_t)(w - (char*)d_ws);
    w = alignp(w);
    int* bsum  = (int*)w;            w += 512 * 4;
    int* boff  = (int*)w;            w += 513 * 4;
    w = alignp(w);
    int* segptr = (int*)w;           w += (size_t)(NSEG + 1) * 4;
    w = alignp(w);
    int* cursor = (int*)w;           w += (size_t)NSEG * 4;
    w = alignp(w);
    unsigned* esrc = (unsigned*)w;   w += (size_t)E * 4;
    w = alignp(w);
    us* xh     = (us*)w;             w += (size_t)N * G * 2;
    w = alignp(w);
    us* xrh    = (us*)w;             w += (size_t)N * OUTW * 2;
    w = alignp(w);
    ushort4* Btr = (ushort4*)w;      w += (size_t)224 * 128 * 8;
    w = alignp(w);
    ushort4* Btq = (ushort4*)w;      w += (size_t)32 * 512 * 8;
    w = alignp(w);
    float* qs  = (float*)w;          w += (size_t)N * 256 * 4;
    w = alignp(w);
    us* kvh    = (us*)w;             w += (size_t)N * 256 * 2;

    hipMemsetAsync(d_ws, 0, zero_bytes, stream);

    int eb = (E + 255) / 256;
    count_kernel<<<eb, 256, 0, stream>>>(ei, et, segcnt, N, E);

    scan_part<<<NB_SCAN, 256, 0, stream>>>(segcnt, bsum, NSEG);
    scan_top<<<1, 512, 0, stream>>>(bsum, boff, segptr, NB_SCAN, NSEG);
    scan_apply<<<NB_SCAN, 256, 0, stream>>>(segcnt, boff, segptr, cursor, NSEG);

    scatter_kernel<<<eb, 256, 0, stream>>>(ei, et, cursor, esrc, N, E);

    int total8 = N * G / 8;
    xhalf_kernel<<<(total8 + 255) / 256, 256, 0, stream>>>(x, xh, total8);

    wconv_rgcn<<<112, 256, 0, stream>>>(Wrel, Wroot, Btr);
    wconv_qkvs<<<64, 256, 0, stream>>>(Wq, Wk, Wv, Wsk, Btq);

    rgcn_fused<<<(N + 63) / 64, 256, 0, stream>>>(xh, segptr, esrc, Btr, brg, xrh, N);

    qkvs_mfma<<<(N + 15) / 16, 256, 0, stream>>>(xrh, Btq, bq, bk, bv, bsk, qs, kvh, N);

    attn_kernel<<<(N + 3) / 4, 256, 0, stream>>>(qs, kvh, segptr, esrc, out, N);

    bnreduce_kernel<<<200, 256, 0, stream>>>(out, bnS, bnQ, N);
    bnstats_kernel<<<1, 128, 0, stream>>>(bnS, bnQ, gamma, beta, bnA, bnB, N);

    int total4 = N * OUTW / 4;
    apply_kernel<<<(total4 + 255) / 256, 256, 0, stream>>>(out, bnA, bnB, total4);
}

// Round 5
// 500.767 us; speedup vs baseline: 1.0502x; 1.0502x over previous
//
#include <hip/hip_runtime.h>
#include <hip/hip_fp16.h>
#include <stdint.h>

#define G      128
#define OUTW   128
#define RNUM   6

typedef unsigned short us;
typedef _Float16 f16x8 __attribute__((ext_vector_type(8)));
typedef float    f32x4 __attribute__((ext_vector_type(4)));

__device__ inline float h2f(us u) { __half h; *(us*)&h = u; return __half2float(h); }
__device__ inline us f2h(float f) { __half h = __float2half(f); return *(us*)&h; }

union FragU { f16x8 v; ushort4 u[2]; };

// ---------------- K1: per-(dst,rel) segment counts ----------------
__global__ void count_kernel(const int* __restrict__ ei, const int* __restrict__ et,
                             int* __restrict__ segcnt, int N, int E) {
    int e = blockIdx.x * blockDim.x + threadIdx.x;
    if (e >= E) return;
    int dst = ei[E + e];
    int r   = et[e];
    atomicAdd(&segcnt[dst * RNUM + r], 1);
}

// ---------------- scan: 3-phase over n = N*RNUM segments ----------------
__global__ __launch_bounds__(256)
void scan_part(const int* __restrict__ cnt, int* __restrict__ bsum, int n) {
    __shared__ int s[256];
    int base = blockIdx.x * 1024, t = threadIdx.x;
    int v = 0;
    for (int j = 0; j < 4; ++j) { int idx = base + j * 256 + t; if (idx < n) v += cnt[idx]; }
    s[t] = v; __syncthreads();
    for (int off = 128; off; off >>= 1) { if (t < off) s[t] += s[t + off]; __syncthreads(); }
    if (!t) bsum[blockIdx.x] = s[0];
}

__global__ __launch_bounds__(512)
void scan_top(const int* __restrict__ bsum, int* __restrict__ boff,
              int* __restrict__ segptr, int nb, int n) {
    __shared__ int s[512];
    int t = threadIdx.x;
    int v = (t < nb) ? bsum[t] : 0;
    s[t] = v;
    __syncthreads();
    for (int off = 1; off < 512; off <<= 1) {
        int y = (t >= off) ? s[t - off] : 0;
        __syncthreads();
        s[t] += y;
        __syncthreads();
    }
    if (t < nb) boff[t + 1] = s[t];
    if (!t) boff[0] = 0;
    if (t == nb - 1) segptr[n] = s[t];     // grand total = E
}

__global__ __launch_bounds__(256)
void scan_apply(const int* __restrict__ cnt, const int* __restrict__ boff,
                int* __restrict__ segptr, int* __restrict__ cursor, int n) {
    __shared__ int L[1024];
    __shared__ int SS[256];
    int base = blockIdx.x * 1024, t = threadIdx.x;
    for (int j = 0; j < 4; ++j) { int idx = base + j * 256 + t; L[j * 256 + t] = (idx < n) ? cnt[idx] : 0; }
    __syncthreads();
    int s0 = L[t*4] + L[t*4+1] + L[t*4+2] + L[t*4+3];
    SS[t] = s0; __syncthreads();
    for (int off = 1; off < 256; off <<= 1) {
        int y = (t >= off) ? SS[t - off] : 0;
        __syncthreads();
        SS[t] += y;
        __syncthreads();
    }
    int e0 = (t ? SS[t - 1] : 0) + boff[blockIdx.x];
    int4 ov;
    int a;
    a = L[t*4+0]; ov.x = e0; e0 += a;
    a = L[t*4+1]; ov.y = e0; e0 += a;
    a = L[t*4+2]; ov.z = e0; e0 += a;
    a = L[t*4+3]; ov.w = e0; e0 += a;
    int idx0 = base + t * 4;
    if (idx0 + 3 < n) {
        *(int4*)(segptr + idx0) = ov;
        *(int4*)(cursor + idx0) = ov;
    } else {
        int vals[4] = {ov.x, ov.y, ov.z, ov.w};
        for (int k = 0; k < 4; ++k)
            if (idx0 + k < n) { segptr[idx0 + k] = vals[k]; cursor[idx0 + k] = vals[k]; }
    }
}

// ---------------- K3: scatter edges into composite CSR ----------------
__global__ void scatter_kernel(const int* __restrict__ ei, const int* __restrict__ et,
                               int* __restrict__ cursor, unsigned* __restrict__ esrc,
                               int N, int E) {
    int e = blockIdx.x * blockDim.x + threadIdx.x;
    if (e >= E) return;
    int src = ei[e];
    int dst = ei[E + e];
    int r   = et[e];
    int pos = atomicAdd(&cursor[dst * RNUM + r], 1);
    esrc[pos] = (unsigned)src;
}

// ---------------- prep: xhalf + wconv_rgcn + wconv_qkvs fused ----------------
// blocks [0,3125): xhalf ; [3125,3237): wconv_rgcn ; [3237,3301): wconv_qkvs
__global__ __launch_bounds__(256)
void prep_kernel(const float* __restrict__ x, us* __restrict__ xh,
                 const float* __restrict__ Wrel, const float* __restrict__ Wroot,
                 ushort4* __restrict__ Btr,
                 const float* __restrict__ Wq, const float* __restrict__ Wk,
                 const float* __restrict__ Wv, const float* __restrict__ Ws,
                 ushort4* __restrict__ Btq, int xblocks) {
    int b = blockIdx.x;
    if (b < xblocks) {
        int i = b * 256 + threadIdx.x;             // i < N*G/8 exactly
        float4 a = ((const float4*)x)[2*i];
        float4 c = ((const float4*)x)[2*i+1];
        ushort4 u0 = { f2h(a.x), f2h(a.y), f2h(a.z), f2h(a.w) };
        ushort4 u1 = { f2h(c.x), f2h(c.y), f2h(c.z), f2h(c.w) };
        ((ushort4*)xh)[2*i]   = u0;
        ((ushort4*)xh)[2*i+1] = u1;
    } else if (b < xblocks + 112) {
        int idx = (b - xblocks) * 256 + threadIdx.x;   // < 224*128 exactly
        int kq = idx >> 7, n = idx & 127;
        ushort4 o;
        us* op = (us*)&o;
#pragma unroll
        for (int i = 0; i < 4; ++i) {
            int k = 4 * kq + i;
            float v = (k < 768) ? Wrel[(size_t)k * 128 + n] : Wroot[(size_t)(k - 768) * 128 + n];
            op[i] = f2h(v);
        }
        Btr[idx] = o;
    } else {
        int idx = (b - xblocks - 112) * 256 + threadIdx.x;  // < 32*512 exactly
        int kq = idx >> 9, n = idx & 511;
        int quad = n >> 7, nl = n & 127;
        const float* W = (quad == 0) ? Wq : (quad == 1) ? Wk : (quad == 2) ? Wv : Ws;
        ushort4 o;
        us* op = (us*)&o;
#pragma unroll
        for (int i = 0; i < 4; ++i) {
            int k = 4 * kq + i;
            op[i] = f2h(W[(size_t)k * 128 + nl]);
        }
        Btq[idx] = o;
    }
}

// ---------------- K4: aggregation (wave/node, batched gathers, scalar rel-flush) ----------------
// Writes means in MFMA A-fragment layout:
//   meanF us-offset = t*12288 + kq*64 + row*4 + half*2 ; kq = r*32 + (l>>1), half = l&1
__global__ __launch_bounds__(256)
void agg_kernel(const us* __restrict__ xh, const int* __restrict__ segptr,
                const unsigned* __restrict__ esrc, us* __restrict__ meanF, int N) {
    const int wv = threadIdx.x >> 6, l = threadIdx.x & 63;
    const int i = blockIdx.x * 4 + wv;
    if (i >= N) return;
    const int t = i >> 4, row = i & 15;
    const int e0 = __builtin_amdgcn_readfirstlane(segptr[i * RNUM]);
    const int e1 = __builtin_amdgcn_readfirstlane(segptr[i * RNUM + RNUM]);

    int rcur = 0;
    int sstart = e0;
    int bnext = __builtin_amdgcn_readfirstlane(segptr[i * RNUM + 1]);
    float2 a = {0.f, 0.f};
    us* wbase = meanF + (size_t)t * 12288 + row * 4 + (l & 1) * 2;
    const int kqo = (l >> 1) * 64;

#define FLUSH() { \
    float sc_ = 1.f / fmaxf((float)(bnext - sstart), 1.f); \
    ushort2 t2_ = { f2h(a.x * sc_), f2h(a.y * sc_) }; \
    *(ushort2*)(wbase + rcur * 2048 + kqo) = t2_; \
    a.x = 0.f; a.y = 0.f; \
    sstart = bnext; ++rcur; \
    if (rcur < RNUM) bnext = __builtin_amdgcn_readfirstlane(segptr[i * RNUM + rcur + 1]); }

#define GET(J) ((unsigned)__shfl((int)pv, (J)))
#define LX(Q)  (*(const ushort2*)(xh + (size_t)(Q) * G + 2 * l))
#define STEP(U) { while (p >= bnext && rcur < RNUM - 1) FLUSH(); \
                  a.x += h2f((U).x); a.y += h2f((U).y); ++p; }

    int p = e0;
    for (int wb = e0; wb < e1; wb += 64) {
        const int nc = min(64, e1 - wb);
        unsigned pv = (wb + l < e1) ? esrc[wb + l] : 0u;
        int j = 0;
        while (j + 8 <= nc) {
            unsigned q0 = GET(j+0), q1 = GET(j+1), q2 = GET(j+2), q3 = GET(j+3);
            unsigned q4 = GET(j+4), q5 = GET(j+5), q6 = GET(j+6), q7 = GET(j+7);
            ushort2 u0 = LX(q0), u1 = LX(q1), u2 = LX(q2), u3 = LX(q3);
            ushort2 u4 = LX(q4), u5 = LX(q5), u6 = LX(q6), u7 = LX(q7);
            STEP(u0); STEP(u1); STEP(u2); STEP(u3);
            STEP(u4); STEP(u5); STEP(u6); STEP(u7);
            j += 8;
        }
        while (j + 2 <= nc) {
            unsigned q0 = GET(j), q1 = GET(j+1);
            ushort2 u0 = LX(q0), u1 = LX(q1);
            STEP(u0); STEP(u1);
            j += 2;
        }
        if (j < nc) {
            unsigned q0 = GET(j);
            ushort2 u0 = LX(q0);
            STEP(u0);
            ++j;
        }
    }
    while (rcur < RNUM) FLUSH();
#undef STEP
#undef LX
#undef GET
#undef FLUSH
}

// ---------------- K5: RGCN GEMM via MFMA, zero-LDS zero-sync ----------------
// A-frags: kqg<192 from meanF (fragment layout), kqg>=192 from xh (row-major via L1).
__global__ __launch_bounds__(256)
void rgcn_mfma2(const us* __restrict__ xh, const us* __restrict__ meanF,
                const ushort4* __restrict__ Btr, const float* __restrict__ brg,
                us* __restrict__ xrh, int N) {
    const int tid = threadIdx.x;
    const int w = tid >> 6, l = tid & 63;
    const int lh = l >> 4, lm = l & 15;
    const int base = blockIdx.x * 64;
    const int ntile = N >> 4;
    const int t  = min(blockIdx.x * 4 + w, ntile - 1);
    const int gr = min(base + w * 16 + lm, N - 1);
    const us* amean = meanF + (size_t)t * 12288 + lm * 4;
    const us* aroot = xh + (size_t)gr * 128;

    f32x4 acc[8];
#pragma unroll
    for (int ct = 0; ct < 8; ++ct) {
        float b = brg[ct * 16 + lm];
        acc[ct] = (f32x4){b, b, b, b};
    }

#pragma unroll
    for (int s = 0; s < 28; ++s) {
        const int kqg = s * 8 + lh;
        FragU af;
        if (s < 24) {
            af.u[0] = *(const ushort4*)(amean + kqg * 64);
            af.u[1] = *(const ushort4*)(amean + (kqg + 4) * 64);
        } else {
            const int kql = kqg - 192;
            af.u[0] = *(const ushort4*)(aroot + kql * 4);
            af.u[1] = *(const ushort4*)(aroot + kql * 4 + 16);
        }
        const ushort4* B0 = Btr + (size_t)kqg * 128 + lm;
        const ushort4* B1 = B0 + 4 * 128;
#pragma unroll
        for (int ct = 0; ct < 8; ++ct) {
            FragU bf;
            bf.u[0] = B0[ct * 16];
            bf.u[1] = B1[ct * 16];
            acc[ct] = __builtin_amdgcn_mfma_f32_16x16x32_f16(af.v, bf.v, acc[ct], 0, 0, 0);
        }
    }

#pragma unroll
    for (int ct = 0; ct < 8; ++ct) {
#pragma unroll
        for (int i = 0; i < 4; ++i) {
            int r = base + w * 16 + 4 * lh + i;
            if (r < N) xrh[(size_t)r * 128 + ct * 16 + lm] = f2h(acc[ct][i]);
        }
    }
}

// ---------------- K6: q|k|v|skip via MFMA, zero-LDS (512 thr, 8 waves) ----------------
__global__ __launch_bounds__(512)
void qkvs_mfma2(const us* __restrict__ xrh, const ushort4* __restrict__ Btq,
                const float* __restrict__ bq, const float* __restrict__ bk,
                const float* __restrict__ bv, const float* __restrict__ bs,
                float* __restrict__ qs, us* __restrict__ kvh, int N) {
    const int tid = threadIdx.x;
    const int w = tid >> 6, l = tid & 63;
    const int quad = w & 3, tp = w >> 2;
    const int lh = l >> 4, lm = l & 15;
    const int base = blockIdx.x * 64;
    const float* bias = (quad == 0) ? bq : (quad == 1) ? bk : (quad == 2) ? bv : bs;

#pragma unroll
    for (int tt = 0; tt < 2; ++tt) {
        const int tile = tp * 2 + tt;
        const int ar = min(base + tile * 16 + lm, N - 1);
        const us* ap = xrh + (size_t)ar * 128;
        f32x4 acc[8];
#pragma unroll
        for (int ct = 0; ct < 8; ++ct) {
            float b = bias[ct * 16 + lm];
            acc[ct] = (f32x4){b, b, b, b};
        }
#pragma unroll
        for (int s = 0; s < 4; ++s) {
            const int kq = s * 8 + lh;
            FragU af;
            af.u[0] = *(const ushort4*)(ap + kq * 4);
            af.u[1] = *(const ushort4*)(ap + kq * 4 + 16);
            const ushort4* B0 = Btq + (size_t)kq * 512 + quad * 128 + lm;
            const ushort4* B1 = B0 + 4 * 512;
#pragma unroll
            for (int ct = 0; ct < 8; ++ct) {
                FragU bf;
                bf.u[0] = B0[ct * 16];
                bf.u[1] = B1[ct * 16];
                acc[ct] = __builtin_amdgcn_mfma_f32_16x16x32_f16(af.v, bf.v, acc[ct], 0, 0, 0);
            }
        }
        if (quad == 0 || quad == 3) {
            int off = (quad == 0) ? 0 : 128;
#pragma unroll
            for (int ct = 0; ct < 8; ++ct)
#pragma unroll
                for (int i = 0; i < 4; ++i) {
                    int r = base + tile * 16 + 4 * lh + i;
                    if (r < N) qs[(size_t)r * 256 + off + ct * 16 + lm] = acc[ct][i];
                }
        } else {
            int off = (quad == 1) ? 0 : 2;
#pragma unroll
            for (int ct = 0; ct < 8; ++ct)
#pragma unroll
                for (int i = 0; i < 4; ++i) {
                    int r = base + tile * 16 + 4 * lh + i;
                    int col = ct * 16 + lm;
                    if (r < N) kvh[(size_t)r * 256 + (col >> 1) * 4 + (col & 1) + off] = f2h(acc[ct][i]);
                }
        }
    }
}

// ---------------- K7: attention (wave/node, online softmax) + BN partials ----------------
__global__ __launch_bounds__(256)
void attn_kernel(const float* __restrict__ qs, const us* __restrict__ kvh,
                 const int* __restrict__ segptr, const unsigned* __restrict__ esrc,
                 float* __restrict__ out, float* __restrict__ bnS,
                 float* __restrict__ bnQ, int N) {
    __shared__ float sS[128], sQ[128];
    const int tid = threadIdx.x;
    if (tid < 128) { sS[tid] = 0.f; sQ[tid] = 0.f; }
    __syncthreads();

    const int wv = tid >> 6, l = tid & 63;
    const int stride = gridDim.x * 4;
    const float QS = 0.17677669529663687f;   // 1/sqrt(32)
    float2 bsum = {0.f, 0.f}, bsq = {0.f, 0.f};

    for (int i = blockIdx.x * 4 + wv; i < N; i += stride) {
        float2 q2 = *(const float2*)(qs + (size_t)i * 256 + 2*l);
        q2.x *= QS; q2.y *= QS;

        float m = -INFINITY, den = 0.f;
        float2 acc = {0.f, 0.f};
        const int e0 = segptr[(size_t)i * RNUM], e1 = segptr[(size_t)i * RNUM + RNUM];

#define KVLOAD(P) (*(const ushort4*)(kvh + (size_t)(P) * 256 + 4*l))
#define SCORE(U, S) { \
    float s_ = q2.x * h2f((U).x) + q2.y * h2f((U).y); \
    s_ += __shfl_xor(s_, 1, 16); s_ += __shfl_xor(s_, 2, 16); \
    s_ += __shfl_xor(s_, 4, 16); s_ += __shfl_xor(s_, 8, 16); \
    S = s_; }

        for (int base = e0; base < e1; base += 64) {
            const int nc = min(64, e1 - base);
            unsigned pv = 0;
            if (base + l < e1) pv = esrc[base + l];
            int j = 0;
            for (; j + 4 <= nc; j += 4) {
                unsigned p0 = (unsigned)__shfl((int)pv, j+0);
                unsigned p1 = (unsigned)__shfl((int)pv, j+1);
                unsigned p2 = (unsigned)__shfl((int)pv, j+2);
                unsigned p3 = (unsigned)__shfl((int)pv, j+3);
                ushort4 k0 = KVLOAD(p0), k1 = KVLOAD(p1), k2 = KVLOAD(p2), k3 = KVLOAD(p3);
                float s0, s1, s2, s3;
                SCORE(k0, s0); SCORE(k1, s1); SCORE(k2, s2); SCORE(k3, s3);
                float mx = fmaxf(fmaxf(fmaxf(s0, s1), fmaxf(s2, s3)), m);
                float rs = __expf(m - mx);
                float p0e = __expf(s0 - mx), p1e = __expf(s1 - mx);
                float p2e = __expf(s2 - mx), p3e = __expf(s3 - mx);
                den = den * rs + ((p0e + p1e) + (p2e + p3e));
                acc.x = acc.x * rs + p0e*h2f(k0.z) + p1e*h2f(k1.z) + p2e*h2f(k2.z) + p3e*h2f(k3.z);
                acc.y = acc.y * rs + p0e*h2f(k0.w) + p1e*h2f(k1.w) + p2e*h2f(k2.w) + p3e*h2f(k3.w);
                m = mx;
            }
            for (; j < nc; ++j) {
                unsigned p0 = (unsigned)__shfl((int)pv, j);
                ushort4 k0 = KVLOAD(p0);
                float s0; SCORE(k0, s0);
                float mx = fmaxf(m, s0);
                float rs = __expf(m - mx);
                float pe = __expf(s0 - mx);
                den = den * rs + pe;
                acc.x = acc.x * rs + pe * h2f(k0.z);
                acc.y = acc.y * rs + pe * h2f(k0.w);
                m = mx;
            }
        }
#undef SCORE
#undef KVLOAD

        float inv = 1.f / (den + 1e-16f);
        float2 sk = *(const float2*)(qs + (size_t)i * 256 + 128 + 2*l);
        float2 o = { acc.x * inv + sk.x, acc.y * inv + sk.y };
        *(float2*)(out + (size_t)i * OUTW + 2*l) = o;
        bsum.x += o.x; bsum.y += o.y;
        bsq.x  += o.x * o.x; bsq.y += o.y * o.y;
    }

    atomicAdd(&sS[2*l],     bsum.x);
    atomicAdd(&sS[2*l + 1], bsum.y);
    atomicAdd(&sQ[2*l],     bsq.x);
    atomicAdd(&sQ[2*l + 1], bsq.y);
    __syncthreads();
    if (tid < 128) {
        atomicAdd(&bnS[tid], sS[tid]);
        atomicAdd(&bnQ[tid], sQ[tid]);
    }
}

// ---------------- K8: BN stats (inline) + apply + LeakyReLU ----------------
__global__ __launch_bounds__(256)
void apply_kernel(float* __restrict__ out, const float* __restrict__ bnS,
                  const float* __restrict__ bnQ, const float* __restrict__ gamma,
                  const float* __restrict__ beta, int N, int total4) {
    __shared__ float A_s[128], B_s[128];
    const int tid = threadIdx.x;
    if (tid < 128) {
        float fN  = (float)N;
        float mu  = bnS[tid] / fN;
        float var = bnQ[tid] / fN - mu * mu;
        float rv  = rsqrtf(var + 1e-5f);
        float A   = rv * gamma[tid];
        A_s[tid] = A;
        B_s[tid] = beta[tid] - mu * A;
    }
    __syncthreads();
    for (int idx4 = blockIdx.x * 256 + tid; idx4 < total4; idx4 += gridDim.x * 256) {
        float4 v = ((const float4*)out)[idx4];
        int c0 = (idx4 * 4) & 127;
        float y;
        y = A_s[c0    ] * v.x + B_s[c0    ]; v.x = (y > 0.f) ? y : 0.01f * y;
        y = A_s[c0 + 1] * v.y + B_s[c0 + 1]; v.y = (y > 0.f) ? y : 0.01f * y;
        y = A_s[c0 + 2] * v.z + B_s[c0 + 2]; v.z = (y > 0.f) ? y : 0.01f * y;
        y = A_s[c0 + 3] * v.w + B_s[c0 + 3]; v.w = (y > 0.f) ? y : 0.01f * y;
        ((float4*)out)[idx4] = v;
    }
}

// ---------------- launch ----------------
static inline char* alignp(char* p) {
    return (char*)(((uintptr_t)p + 255) & ~(uintptr_t)255);
}

extern "C" void kernel_launch(void* const* d_in, const int* in_sizes, int n_in,
                              void* d_out, int out_size, void* d_ws, size_t ws_size,
                              hipStream_t stream) {
    const float* x     = (const float*)d_in[0];
    const int*   ei    = (const int*)  d_in[2];
    const int*   et    = (const int*)  d_in[3];
    const float* Wrel  = (const float*)d_in[4];
    const float* Wroot = (const float*)d_in[5];
    const float* brg   = (const float*)d_in[6];
    const float* Wq    = (const float*)d_in[7];
    const float* bq    = (const float*)d_in[8];
    const float* Wk    = (const float*)d_in[9];
    const float* bk    = (const float*)d_in[10];
    const float* Wv    = (const float*)d_in[11];
    const float* bv    = (const float*)d_in[12];
    const float* Wsk   = (const float*)d_in[13];
    const float* bsk   = (const float*)d_in[14];
    const float* gamma = (const float*)d_in[15];
    const float* beta  = (const float*)d_in[16];
    float* out = (float*)d_out;

    const int N = in_sizes[0] / G;
    const int E = in_sizes[3];
    const int NSEG = N * RNUM;
    const int NB_SCAN = (NSEG + 1023) / 1024;   // <= 512

    // ---- workspace carve ----
    char* w = (char*)d_ws;
    int* segcnt = (int*)w;           w += (size_t)NSEG * 4;
    float* bnS = (float*)w;          w += 128 * 4;
    float* bnQ = (float*)w;          w += 128 * 4;
    size_t zero_bytes = (size_t)(w - (char*)d_ws);
    w = alignp(w);
    int* bsum  = (int*)w;            w += 512 * 4;
    int* boff  = (int*)w;            w += 513 * 4;
    w = alignp(w);
    int* segptr = (int*)w;           w += (size_t)(NSEG + 1) * 4;
    w = alignp(w);
    int* cursor = (int*)w;           w += (size_t)NSEG * 4;
    w = alignp(w);
    unsigned* esrc = (unsigned*)w;   w += (size_t)E * 4;
    w = alignp(w);
    us* xh     = (us*)w;             w += (size_t)N * G * 2;
    w = alignp(w);
    us* xrh    = (us*)w;             w += (size_t)N * OUTW * 2;
    w = alignp(w);
    ushort4* Btr = (ushort4*)w;      w += (size_t)224 * 128 * 8;
    w = alignp(w);
    ushort4* Btq = (ushort4*)w;      w += (size_t)32 * 512 * 8;
    w = alignp(w);
    // aliased region: meanF [N/16][192][16][4] fp16 (76.8MB);
    // later qs [N][256] f32 (51.2MB) + kvh [N][256] fp16 (25.6MB)
    us*    meanF = (us*)w;
    float* qs    = (float*)w;
    us*    kvh   = (us*)(w + (size_t)N * 256 * 4);

    hipMemsetAsync(d_ws, 0, zero_bytes, stream);

    int eb = (E + 255) / 256;
    count_kernel<<<eb, 256, 0, stream>>>(ei, et, segcnt, N, E);

    scan_part<<<NB_SCAN, 256, 0, stream>>>(segcnt, bsum, NSEG);
    scan_top<<<1, 512, 0, stream>>>(bsum, boff, segptr, NB_SCAN, NSEG);
    scan_apply<<<NB_SCAN, 256, 0, stream>>>(segcnt, boff, segptr, cursor, NSEG);

    scatter_kernel<<<eb, 256, 0, stream>>>(ei, et, cursor, esrc, N, E);

    int xblocks = N * G / 8 / 256;               // 3125
    prep_kernel<<<xblocks + 112 + 64, 256, 0, stream>>>(x, xh, Wrel, Wroot, Btr,
                                                        Wq, Wk, Wv, Wsk, Btq, xblocks);

    agg_kernel<<<(N + 3) / 4, 256, 0, stream>>>(xh, segptr, esrc, meanF, N);

    rgcn_mfma2<<<(N + 63) / 64, 256, 0, stream>>>(xh, meanF, Btr, brg, xrh, N);

    qkvs_mfma2<<<(N + 63) / 64, 512, 0, stream>>>(xrh, Btq, bq, bk, bv, bsk, qs, kvh, N);

    attn_kernel<<<2048, 256, 0, stream>>>(qs, kvh, segptr, esrc, out, bnS, bnQ, N);

    int total4 = N * OUTW / 4;
    apply_kernel<<<2048, 256, 0, stream>>>(out, bnS, bnQ, gamma, beta, N, total4);
}

// Round 6
// 453.861 us; speedup vs baseline: 1.1588x; 1.1033x over previous
//
#include <hip/hip_runtime.h>
#include <hip/hip_fp16.h>
#include <stdint.h>

#define G      128
#define OUTW   128
#define RNUM   6

typedef unsigned short us;
typedef _Float16 f16x8 __attribute__((ext_vector_type(8)));
typedef float    f32x4 __attribute__((ext_vector_type(4)));

__device__ inline float h2f(us u) { __half h; *(us*)&h = u; return __half2float(h); }
__device__ inline us f2h(float f) { __half h = __float2half(f); return *(us*)&h; }
__device__ inline float2 h22(int u) { return __half22float2(*(__half2*)&u); }

union FragU { f16x8 v; ushort4 u[2]; };

// ---------------- K1: per-(dst,rel) segment counts ----------------
__global__ void count_kernel(const int* __restrict__ ei, const int* __restrict__ et,
                             int* __restrict__ segcnt, int N, int E) {
    int e = blockIdx.x * blockDim.x + threadIdx.x;
    if (e >= E) return;
    int dst = ei[E + e];
    int r   = et[e];
    atomicAdd(&segcnt[dst * RNUM + r], 1);
}

// ---------------- scan: 3-phase over n = N*RNUM segments ----------------
__global__ __launch_bounds__(256)
void scan_part(const int* __restrict__ cnt, int* __restrict__ bsum, int n) {
    __shared__ int s[256];
    int base = blockIdx.x * 1024, t = threadIdx.x;
    int v = 0;
    for (int j = 0; j < 4; ++j) { int idx = base + j * 256 + t; if (idx < n) v += cnt[idx]; }
    s[t] = v; __syncthreads();
    for (int off = 128; off; off >>= 1) { if (t < off) s[t] += s[t + off]; __syncthreads(); }
    if (!t) bsum[blockIdx.x] = s[0];
}

__global__ __launch_bounds__(512)
void scan_top(const int* __restrict__ bsum, int* __restrict__ boff,
              int* __restrict__ segptr, int nb, int n) {
    __shared__ int s[512];
    int t = threadIdx.x;
    int v = (t < nb) ? bsum[t] : 0;
    s[t] = v;
    __syncthreads();
    for (int off = 1; off < 512; off <<= 1) {
        int y = (t >= off) ? s[t - off] : 0;
        __syncthreads();
        s[t] += y;
        __syncthreads();
    }
    if (t < nb) boff[t + 1] = s[t];
    if (!t) boff[0] = 0;
    if (t == nb - 1) segptr[n] = s[t];     // grand total = E
}

__global__ __launch_bounds__(256)
void scan_apply(const int* __restrict__ cnt, const int* __restrict__ boff,
                int* __restrict__ segptr, int* __restrict__ cursor, int n) {
    __shared__ int L[1024];
    __shared__ int SS[256];
    int base = blockIdx.x * 1024, t = threadIdx.x;
    for (int j = 0; j < 4; ++j) { int idx = base + j * 256 + t; L[j * 256 + t] = (idx < n) ? cnt[idx] : 0; }
    __syncthreads();
    int s0 = L[t*4] + L[t*4+1] + L[t*4+2] + L[t*4+3];
    SS[t] = s0; __syncthreads();
    for (int off = 1; off < 256; off <<= 1) {
        int y = (t >= off) ? SS[t - off] : 0;
        __syncthreads();
        SS[t] += y;
        __syncthreads();
    }
    int e0 = (t ? SS[t - 1] : 0) + boff[blockIdx.x];
    int4 ov;
    int a;
    a = L[t*4+0]; ov.x = e0; e0 += a;
    a = L[t*4+1]; ov.y = e0; e0 += a;
    a = L[t*4+2]; ov.z = e0; e0 += a;
    a = L[t*4+3]; ov.w = e0; e0 += a;
    int idx0 = base + t * 4;
    if (idx0 + 3 < n) {
        *(int4*)(segptr + idx0) = ov;
        *(int4*)(cursor + idx0) = ov;
    } else {
        int vals[4] = {ov.x, ov.y, ov.z, ov.w};
        for (int k = 0; k < 4; ++k)
            if (idx0 + k < n) { segptr[idx0 + k] = vals[k]; cursor[idx0 + k] = vals[k]; }
    }
}

// ---------------- K3: scatter edges into composite CSR ----------------
__global__ void scatter_kernel(const int* __restrict__ ei, const int* __restrict__ et,
                               int* __restrict__ cursor, unsigned* __restrict__ esrc,
                               int N, int E) {
    int e = blockIdx.x * blockDim.x + threadIdx.x;
    if (e >= E) return;
    int src = ei[e];
    int dst = ei[E + e];
    int r   = et[e];
    int pos = atomicAdd(&cursor[dst * RNUM + r], 1);
    esrc[pos] = (unsigned)src;
}

// ---------------- prep: xhalf + wconv_rgcn + wconv_qkvs fused ----------------
__global__ __launch_bounds__(256)
void prep_kernel(const float* __restrict__ x, us* __restrict__ xh,
                 const float* __restrict__ Wrel, const float* __restrict__ Wroot,
                 ushort4* __restrict__ Btr,
                 const float* __restrict__ Wq, const float* __restrict__ Wk,
                 const float* __restrict__ Wv, const float* __restrict__ Ws,
                 ushort4* __restrict__ Btq, int xblocks) {
    int b = blockIdx.x;
    if (b < xblocks) {
        int i = b * 256 + threadIdx.x;             // i < N*G/8 exactly
        float4 a = ((const float4*)x)[2*i];
        float4 c = ((const float4*)x)[2*i+1];
        ushort4 u0 = { f2h(a.x), f2h(a.y), f2h(a.z), f2h(a.w) };
        ushort4 u1 = { f2h(c.x), f2h(c.y), f2h(c.z), f2h(c.w) };
        ((ushort4*)xh)[2*i]   = u0;
        ((ushort4*)xh)[2*i+1] = u1;
    } else if (b < xblocks + 112) {
        int idx = (b - xblocks) * 256 + threadIdx.x;   // < 224*128 exactly
        int kq = idx >> 7, n = idx & 127;
        ushort4 o;
        us* op = (us*)&o;
#pragma unroll
        for (int i = 0; i < 4; ++i) {
            int k = 4 * kq + i;
            float v = (k < 768) ? Wrel[(size_t)k * 128 + n] : Wroot[(size_t)(k - 768) * 128 + n];
            op[i] = f2h(v);
        }
        Btr[idx] = o;
    } else {
        int idx = (b - xblocks - 112) * 256 + threadIdx.x;  // < 32*512 exactly
        int kq = idx >> 9, n = idx & 511;
        int quad = n >> 7, nl = n & 127;
        const float* W = (quad == 0) ? Wq : (quad == 1) ? Wk : (quad == 2) ? Wv : Ws;
        ushort4 o;
        us* op = (us*)&o;
#pragma unroll
        for (int i = 0; i < 4; ++i) {
            int k = 4 * kq + i;
            op[i] = f2h(W[(size_t)k * 128 + nl]);
        }
        Btq[idx] = o;
    }
}

// ---------------- K4: aggregation (wave/node, batched gathers, scalar rel-flush) ----------------
// meanF us-offset = t*12288 + kq*64 + row*4 + half*2 ; kq = r*32 + (l>>1), half = l&1
__global__ __launch_bounds__(256)
void agg_kernel(const us* __restrict__ xh, const int* __restrict__ segptr,
                const unsigned* __restrict__ esrc, us* __restrict__ meanF, int N) {
    const int wv = threadIdx.x >> 6, l = threadIdx.x & 63;
    const int i = blockIdx.x * 4 + wv;
    if (i >= N) return;
    const int t = i >> 4, row = i & 15;
    const int e0 = __builtin_amdgcn_readfirstlane(segptr[i * RNUM]);
    const int e1 = __builtin_amdgcn_readfirstlane(segptr[i * RNUM + RNUM]);

    int rcur = 0;
    int sstart = e0;
    int bnext = __builtin_amdgcn_readfirstlane(segptr[i * RNUM + 1]);
    float2 a = {0.f, 0.f};
    us* wbase = meanF + (size_t)t * 12288 + row * 4 + (l & 1) * 2;
    const int kqo = (l >> 1) * 64;

#define FLUSH() { \
    float sc_ = 1.f / fmaxf((float)(bnext - sstart), 1.f); \
    ushort2 t2_ = { f2h(a.x * sc_), f2h(a.y * sc_) }; \
    *(ushort2*)(wbase + rcur * 2048 + kqo) = t2_; \
    a.x = 0.f; a.y = 0.f; \
    sstart = bnext; ++rcur; \
    if (rcur < RNUM) bnext = __builtin_amdgcn_readfirstlane(segptr[i * RNUM + rcur + 1]); }

#define GET(J) ((unsigned)__shfl((int)pv, (J)))
#define LX(Q)  (*(const ushort2*)(xh + (size_t)(Q) * G + 2 * l))
#define STEP(U) { while (p >= bnext && rcur < RNUM - 1) FLUSH(); \
                  a.x += h2f((U).x); a.y += h2f((U).y); ++p; }

    int p = e0;
    for (int wb = e0; wb < e1; wb += 64) {
        const int nc = min(64, e1 - wb);
        unsigned pv = (wb + l < e1) ? esrc[wb + l] : 0u;
        int j = 0;
        while (j + 8 <= nc) {
            unsigned q0 = GET(j+0), q1 = GET(j+1), q2 = GET(j+2), q3 = GET(j+3);
            unsigned q4 = GET(j+4), q5 = GET(j+5), q6 = GET(j+6), q7 = GET(j+7);
            ushort2 u0 = LX(q0), u1 = LX(q1), u2 = LX(q2), u3 = LX(q3);
            ushort2 u4 = LX(q4), u5 = LX(q5), u6 = LX(q6), u7 = LX(q7);
            STEP(u0); STEP(u1); STEP(u2); STEP(u3);
            STEP(u4); STEP(u5); STEP(u6); STEP(u7);
            j += 8;
        }
        while (j + 2 <= nc) {
            unsigned q0 = GET(j), q1 = GET(j+1);
            ushort2 u0 = LX(q0), u1 = LX(q1);
            STEP(u0); STEP(u1);
            j += 2;
        }
        if (j < nc) {
            unsigned q0 = GET(j);
            ushort2 u0 = LX(q0);
            STEP(u0);
            ++j;
        }
    }
    while (rcur < RNUM) FLUSH();
#undef STEP
#undef LX
#undef GET
#undef FLUSH
}

// ---------------- K5: RGCN GEMM via MFMA, B-fragment register reuse ----------------
// 256 thr / 4 waves; wave owns 32 rows (2 x 16-row A-frag tiles); block = 128 rows.
__global__ __launch_bounds__(256)
void rgcn_mfma3(const us* __restrict__ xh, const us* __restrict__ meanF,
                const ushort4* __restrict__ Btr, const float* __restrict__ brg,
                us* __restrict__ xrh, int N) {
    const int tid = threadIdx.x;
    const int w = tid >> 6, l = tid & 63;
    const int lh = l >> 4, lm = l & 15;
    const int rowbase = blockIdx.x * 128 + w * 32;
    const int ntile = N >> 4;

    const us* amean[2];
    const us* aroot[2];
#pragma unroll
    for (int tt = 0; tt < 2; ++tt) {
        int t  = min((rowbase >> 4) + tt, ntile - 1);
        int gr = min(rowbase + tt * 16 + lm, N - 1);
        amean[tt] = meanF + (size_t)t * 12288 + lm * 4;
        aroot[tt] = xh + (size_t)gr * 128;
    }

    f32x4 acc[2][8];
#pragma unroll
    for (int tt = 0; tt < 2; ++tt)
#pragma unroll
        for (int ct = 0; ct < 8; ++ct) {
            float b = brg[ct * 16 + lm];
            acc[tt][ct] = (f32x4){b, b, b, b};
        }

    // means part: kqg 0..191
    for (int s = 0; s < 24; ++s) {
        const int kqg = s * 8 + lh;
        const ushort4* B0 = Btr + (size_t)kqg * 128 + lm;
        const ushort4* B1 = B0 + 4 * 128;
        FragU bf[8];
#pragma unroll
        for (int ct = 0; ct < 8; ++ct) { bf[ct].u[0] = B0[ct * 16]; bf[ct].u[1] = B1[ct * 16]; }
#pragma unroll
        for (int tt = 0; tt < 2; ++tt) {
            FragU af;
            af.u[0] = *(const ushort4*)(amean[tt] + kqg * 64);
            af.u[1] = *(const ushort4*)(amean[tt] + (kqg + 4) * 64);
#pragma unroll
            for (int ct = 0; ct < 8; ++ct)
                acc[tt][ct] = __builtin_amdgcn_mfma_f32_16x16x32_f16(af.v, bf[ct].v, acc[tt][ct], 0, 0, 0);
        }
    }
    // root part: kqg 192..223
#pragma unroll
    for (int s = 0; s < 4; ++s) {
        const int kql = s * 8 + lh;
        const int kqg = 192 + kql;
        const ushort4* B0 = Btr + (size_t)kqg * 128 + lm;
        const ushort4* B1 = B0 + 4 * 128;
        FragU bf[8];
#pragma unroll
        for (int ct = 0; ct < 8; ++ct) { bf[ct].u[0] = B0[ct * 16]; bf[ct].u[1] = B1[ct * 16]; }
#pragma unroll
        for (int tt = 0; tt < 2; ++tt) {
            FragU af;
            af.u[0] = *(const ushort4*)(aroot[tt] + kql * 4);
            af.u[1] = *(const ushort4*)(aroot[tt] + kql * 4 + 16);
#pragma unroll
            for (int ct = 0; ct < 8; ++ct)
                acc[tt][ct] = __builtin_amdgcn_mfma_f32_16x16x32_f16(af.v, bf[ct].v, acc[tt][ct], 0, 0, 0);
        }
    }

#pragma unroll
    for (int tt = 0; tt < 2; ++tt)
#pragma unroll
        for (int ct = 0; ct < 8; ++ct)
#pragma unroll
            for (int i = 0; i < 4; ++i) {
                int r = rowbase + tt * 16 + 4 * lh + i;
                if (r < N) xrh[(size_t)r * 128 + ct * 16 + lm] = f2h(acc[tt][ct][i]);
            }
}

// ---------------- K6: q|k|v|skip via MFMA, all-fp16 outputs ----------------
// 256 thr / 4 waves; wave = one quad over 32 rows (2 tiles); block = 32 rows.
__global__ __launch_bounds__(256)
void qkvs_mfma3(const us* __restrict__ xrh, const ushort4* __restrict__ Btq,
                const float* __restrict__ bq, const float* __restrict__ bk,
                const float* __restrict__ bv, const float* __restrict__ bs,
                us* __restrict__ qsh, us* __restrict__ kvh, int N) {
    const int tid = threadIdx.x;
    const int quad = tid >> 6, l = tid & 63;
    const int lh = l >> 4, lm = l & 15;
    const int base = blockIdx.x * 32;
    const float* bias = (quad == 0) ? bq : (quad == 1) ? bk : (quad == 2) ? bv : bs;

    const us* ap[2];
#pragma unroll
    for (int tt = 0; tt < 2; ++tt) {
        int ar = min(base + tt * 16 + lm, N - 1);
        ap[tt] = xrh + (size_t)ar * 128;
    }

    f32x4 acc[2][8];
#pragma unroll
    for (int tt = 0; tt < 2; ++tt)
#pragma unroll
        for (int ct = 0; ct < 8; ++ct) {
            float b = bias[ct * 16 + lm];
            acc[tt][ct] = (f32x4){b, b, b, b};
        }

#pragma unroll
    for (int s = 0; s < 4; ++s) {
        const int kq = s * 8 + lh;
        const ushort4* B0 = Btq + (size_t)kq * 512 + quad * 128 + lm;
        const ushort4* B1 = B0 + 4 * 512;
        FragU bf[8];
#pragma unroll
        for (int ct = 0; ct < 8; ++ct) { bf[ct].u[0] = B0[ct * 16]; bf[ct].u[1] = B1[ct * 16]; }
#pragma unroll
        for (int tt = 0; tt < 2; ++tt) {
            FragU af;
            af.u[0] = *(const ushort4*)(ap[tt] + kq * 4);
            af.u[1] = *(const ushort4*)(ap[tt] + kq * 4 + 16);
#pragma unroll
            for (int ct = 0; ct < 8; ++ct)
                acc[tt][ct] = __builtin_amdgcn_mfma_f32_16x16x32_f16(af.v, bf[ct].v, acc[tt][ct], 0, 0, 0);
        }
    }

    if (quad == 0 || quad == 3) {
        const int off = (quad == 0) ? 0 : 128;
#pragma unroll
        for (int tt = 0; tt < 2; ++tt)
#pragma unroll
            for (int ct = 0; ct < 8; ++ct)
#pragma unroll
                for (int i = 0; i < 4; ++i) {
                    int r = base + tt * 16 + 4 * lh + i;
                    if (r < N) qsh[(size_t)r * 256 + off + ct * 16 + lm] = f2h(acc[tt][ct][i]);
                }
    } else {
        const int off = (quad == 1) ? 0 : 2;
#pragma unroll
        for (int tt = 0; tt < 2; ++tt)
#pragma unroll
            for (int ct = 0; ct < 8; ++ct)
#pragma unroll
                for (int i = 0; i < 4; ++i) {
                    int r = base + tt * 16 + 4 * lh + i;
                    int col = ct * 16 + lm;
                    if (r < N) kvh[(size_t)r * 256 + (col >> 1) * 4 + (col & 1) + off] = f2h(acc[tt][ct][i]);
                }
    }
}

// ---------------- K7: attention — 32 lanes/node, 2 nodes/wave, online softmax + BN ----------------
__global__ __launch_bounds__(256)
void attn_kernel(const us* __restrict__ qsh, const us* __restrict__ kvh,
                 const int* __restrict__ segptr, const unsigned* __restrict__ esrc,
                 float* __restrict__ out, float* __restrict__ bnS,
                 float* __restrict__ bnQ, int N) {
    __shared__ float sS[128], sQ[128];
    const int tid = threadIdx.x;
    if (tid < 128) { sS[tid] = 0.f; sQ[tid] = 0.f; }
    __syncthreads();

    const int wv = tid >> 6, l = tid & 63;
    const int hh = l >> 5, ll = l & 31;
    const int stride = gridDim.x * 8;
    const float QS = 0.17677669529663687f;   // 1/sqrt(32)
    float4 bsum = {0,0,0,0}, bsq = {0,0,0,0};

#define SCORE(D, S) { \
    float2 ka_ = h22((D).x), kb_ = h22((D).z); \
    float t_ = q4.x*ka_.x + q4.y*ka_.y + q4.z*kb_.x + q4.w*kb_.y; \
    t_ += __shfl_xor(t_, 1, 8); t_ += __shfl_xor(t_, 2, 8); t_ += __shfl_xor(t_, 4, 8); \
    S = t_; }

    for (int ibase = blockIdx.x * 8 + wv * 2; ibase < N; ibase += stride) {
        const bool act = (ibase + hh) < N;
        const int i = min(ibase + hh, N - 1);

        int2 qu = *(const int2*)(qsh + (size_t)i * 256 + 4 * ll);
        float2 qa = h22(qu.x), qb = h22(qu.y);
        float4 q4 = { qa.x * QS, qa.y * QS, qb.x * QS, qb.y * QS };

        float m = -INFINITY, den = 0.f;
        float4 acc = {0,0,0,0};
        const int e0 = segptr[(size_t)i * RNUM], e1 = segptr[(size_t)i * RNUM + RNUM];

        for (int wb = e0; wb < e1; wb += 32) {
            const int nc = min(32, e1 - wb);
            unsigned pv = (wb + ll < e1) ? esrc[wb + ll] : 0u;
            int j = 0;
            for (; j + 4 <= nc; j += 4) {
                unsigned p0 = (unsigned)__shfl((int)pv, j+0, 32);
                unsigned p1 = (unsigned)__shfl((int)pv, j+1, 32);
                unsigned p2 = (unsigned)__shfl((int)pv, j+2, 32);
                unsigned p3 = (unsigned)__shfl((int)pv, j+3, 32);
                int4 d0 = *(const int4*)(kvh + (size_t)p0 * 256 + 8 * ll);
                int4 d1 = *(const int4*)(kvh + (size_t)p1 * 256 + 8 * ll);
                int4 d2 = *(const int4*)(kvh + (size_t)p2 * 256 + 8 * ll);
                int4 d3 = *(const int4*)(kvh + (size_t)p3 * 256 + 8 * ll);
                float s0, s1, s2, s3;
                SCORE(d0, s0); SCORE(d1, s1); SCORE(d2, s2); SCORE(d3, s3);
                float mx = fmaxf(m, fmaxf(fmaxf(s0, s1), fmaxf(s2, s3)));
                float rs = __expf(m - mx);
                float w0 = __expf(s0 - mx), w1 = __expf(s1 - mx);
                float w2 = __expf(s2 - mx), w3 = __expf(s3 - mx);
                den = den * rs + ((w0 + w1) + (w2 + w3));
                float2 va0 = h22(d0.y), vb0 = h22(d0.w);
                float2 va1 = h22(d1.y), vb1 = h22(d1.w);
                float2 va2 = h22(d2.y), vb2 = h22(d2.w);
                float2 va3 = h22(d3.y), vb3 = h22(d3.w);
                acc.x = acc.x * rs + w0*va0.x + w1*va1.x + w2*va2.x + w3*va3.x;
                acc.y = acc.y * rs + w0*va0.y + w1*va1.y + w2*va2.y + w3*va3.y;
                acc.z = acc.z * rs + w0*vb0.x + w1*vb1.x + w2*vb2.x + w3*vb3.x;
                acc.w = acc.w * rs + w0*vb0.y + w1*vb1.y + w2*vb2.y + w3*vb3.y;
                m = mx;
            }
            for (; j < nc; ++j) {
                unsigned p0 = (unsigned)__shfl((int)pv, j, 32);
                int4 d0 = *(const int4*)(kvh + (size_t)p0 * 256 + 8 * ll);
                float s0; SCORE(d0, s0);
                float mx = fmaxf(m, s0);
                float rs = __expf(m - mx);
                float w0 = __expf(s0 - mx);
                den = den * rs + w0;
                float2 va0 = h22(d0.y), vb0 = h22(d0.w);
                acc.x = acc.x * rs + w0 * va0.x;
                acc.y = acc.y * rs + w0 * va0.y;
                acc.z = acc.z * rs + w0 * vb0.x;
                acc.w = acc.w * rs + w0 * vb0.y;
                m = mx;
            }
        }

        float inv = 1.f / (den + 1e-16f);
        int2 su = *(const int2*)(qsh + (size_t)i * 256 + 128 + 4 * ll);
        float2 sa = h22(su.x), sb = h22(su.y);
        float4 o = { acc.x * inv + sa.x, acc.y * inv + sa.y,
                     acc.z * inv + sb.x, acc.w * inv + sb.y };
        if (act) {
            *(float4*)(out + (size_t)i * OUTW + 4 * ll) = o;
            bsum.x += o.x; bsum.y += o.y; bsum.z += o.z; bsum.w += o.w;
            bsq.x += o.x*o.x; bsq.y += o.y*o.y; bsq.z += o.z*o.z; bsq.w += o.w*o.w;
        }
    }
#undef SCORE

    atomicAdd(&sS[4*ll + 0], bsum.x);
    atomicAdd(&sS[4*ll + 1], bsum.y);
    atomicAdd(&sS[4*ll + 2], bsum.z);
    atomicAdd(&sS[4*ll + 3], bsum.w);
    atomicAdd(&sQ[4*ll + 0], bsq.x);
    atomicAdd(&sQ[4*ll + 1], bsq.y);
    atomicAdd(&sQ[4*ll + 2], bsq.z);
    atomicAdd(&sQ[4*ll + 3], bsq.w);
    __syncthreads();
    if (tid < 128) {
        atomicAdd(&bnS[tid], sS[tid]);
        atomicAdd(&bnQ[tid], sQ[tid]);
    }
}

// ---------------- K8: BN stats (inline) + apply + LeakyReLU ----------------
__global__ __launch_bounds__(256)
void apply_kernel(float* __restrict__ out, const float* __restrict__ bnS,
                  const float* __restrict__ bnQ, const float* __restrict__ gamma,
                  const float* __restrict__ beta, int N, int total4) {
    __shared__ float A_s[128], B_s[128];
    const int tid = threadIdx.x;
    if (tid < 128) {
        float fN  = (float)N;
        float mu  = bnS[tid] / fN;
        float var = bnQ[tid] / fN - mu * mu;
        float rv  = rsqrtf(var + 1e-5f);
        float A   = rv * gamma[tid];
        A_s[tid] = A;
        B_s[tid] = beta[tid] - mu * A;
    }
    __syncthreads();
    for (int idx4 = blockIdx.x * 256 + tid; idx4 < total4; idx4 += gridDim.x * 256) {
        float4 v = ((const float4*)out)[idx4];
        int c0 = (idx4 * 4) & 127;
        float y;
        y = A_s[c0    ] * v.x + B_s[c0    ]; v.x = (y > 0.f) ? y : 0.01f * y;
        y = A_s[c0 + 1] * v.y + B_s[c0 + 1]; v.y = (y > 0.f) ? y : 0.01f * y;
        y = A_s[c0 + 2] * v.z + B_s[c0 + 2]; v.z = (y > 0.f) ? y : 0.01f * y;
        y = A_s[c0 + 3] * v.w + B_s[c0 + 3]; v.w = (y > 0.f) ? y : 0.01f * y;
        ((float4*)out)[idx4] = v;
    }
}

// ---------------- launch ----------------
static inline char* alignp(char* p) {
    return (char*)(((uintptr_t)p + 255) & ~(uintptr_t)255);
}

extern "C" void kernel_launch(void* const* d_in, const int* in_sizes, int n_in,
                              void* d_out, int out_size, void* d_ws, size_t ws_size,
                              hipStream_t stream) {
    const float* x     = (const float*)d_in[0];
    const int*   ei    = (const int*)  d_in[2];
    const int*   et    = (const int*)  d_in[3];
    const float* Wrel  = (const float*)d_in[4];
    const float* Wroot = (const float*)d_in[5];
    const float* brg   = (const float*)d_in[6];
    const float* Wq    = (const float*)d_in[7];
    const float* bq    = (const float*)d_in[8];
    const float* Wk    = (const float*)d_in[9];
    const float* bk    = (const float*)d_in[10];
    const float* Wv    = (const float*)d_in[11];
    const float* bv    = (const float*)d_in[12];
    const float* Wsk   = (const float*)d_in[13];
    const float* bsk   = (const float*)d_in[14];
    const float* gamma = (const float*)d_in[15];
    const float* beta  = (const float*)d_in[16];
    float* out = (float*)d_out;

    const int N = in_sizes[0] / G;
    const int E = in_sizes[3];
    const int NSEG = N * RNUM;
    const int NB_SCAN = (NSEG + 1023) / 1024;   // <= 512

    // ---- workspace carve ----
    char* w = (char*)d_ws;
    int* segcnt = (int*)w;           w += (size_t)NSEG * 4;
    float* bnS = (float*)w;          w += 128 * 4;
    float* bnQ = (float*)w;          w += 128 * 4;
    size_t zero_bytes = (size_t)(w - (char*)d_ws);
    w = alignp(w);
    int* bsum  = (int*)w;            w += 512 * 4;
    int* boff  = (int*)w;            w += 513 * 4;
    w = alignp(w);
    int* segptr = (int*)w;           w += (size_t)(NSEG + 1) * 4;
    w = alignp(w);
    int* cursor = (int*)w;           w += (size_t)NSEG * 4;
    w = alignp(w);
    unsigned* esrc = (unsigned*)w;   w += (size_t)E * 4;
    w = alignp(w);
    us* xh     = (us*)w;             w += (size_t)N * G * 2;
    w = alignp(w);
    us* xrh    = (us*)w;             w += (size_t)N * OUTW * 2;
    w = alignp(w);
    ushort4* Btr = (ushort4*)w;      w += (size_t)224 * 128 * 8;
    w = alignp(w);
    ushort4* Btq = (ushort4*)w;      w += (size_t)32 * 512 * 8;
    w = alignp(w);
    // aliased region: meanF [N/16][192][16][4] fp16 (76.8MB);
    // later qsh [N][256] fp16 (25.6MB) + kvh [N][256] fp16 (25.6MB)
    us* meanF = (us*)w;
    us* qsh   = (us*)w;
    us* kvh   = (us*)(w + (size_t)N * 256 * 2);

    hipMemsetAsync(d_ws, 0, zero_bytes, stream);

    int eb = (E + 255) / 256;
    count_kernel<<<eb, 256, 0, stream>>>(ei, et, segcnt, N, E);

    scan_part<<<NB_SCAN, 256, 0, stream>>>(segcnt, bsum, NSEG);
    scan_top<<<1, 512, 0, stream>>>(bsum, boff, segptr, NB_SCAN, NSEG);
    scan_apply<<<NB_SCAN, 256, 0, stream>>>(segcnt, boff, segptr, cursor, NSEG);

    scatter_kernel<<<eb, 256, 0, stream>>>(ei, et, cursor, esrc, N, E);

    int xblocks = N * G / 8 / 256;               // 3125
    prep_kernel<<<xblocks + 112 + 64, 256, 0, stream>>>(x, xh, Wrel, Wroot, Btr,
                                                        Wq, Wk, Wv, Wsk, Btq, xblocks);

    agg_kernel<<<(N + 3) / 4, 256, 0, stream>>>(xh, segptr, esrc, meanF, N);

    rgcn_mfma3<<<(N + 127) / 128, 256, 0, stream>>>(xh, meanF, Btr, brg, xrh, N);

    qkvs_mfma3<<<(N + 31) / 32, 256, 0, stream>>>(xrh, Btq, bq, bk, bv, bsk, qsh, kvh, N);

    attn_kernel<<<2048, 256, 0, stream>>>(qsh, kvh, segptr, esrc, out, bnS, bnQ, N);

    int total4 = N * OUTW / 4;
    apply_kernel<<<2048, 256, 0, stream>>>(out, bnS, bnQ, gamma, beta, N, total4);
}

// Round 7
// 436.903 us; speedup vs baseline: 1.2037x; 1.0388x over previous
//
#include <hip/hip_runtime.h>
#include <hip/hip_fp16.h>
#include <stdint.h>

#define G      128
#define OUTW   128
#define RNUM   6

typedef unsigned short us;
typedef _Float16 f16x8 __attribute__((ext_vector_type(8)));
typedef float    f32x4 __attribute__((ext_vector_type(4)));

__device__ inline float h2f(us u) { __half h; *(us*)&h = u; return __half2float(h); }
__device__ inline us f2h(float f) { __half h = __float2half(f); return *(us*)&h; }
__device__ inline float2 h22(int u) { return __half22float2(*(__half2*)&u); }

union FragU { f16x8 v; ushort4 u[2]; };

// ---------------- K1: per-(dst,rel) segment counts ----------------
__global__ void count_kernel(const int* __restrict__ ei, const int* __restrict__ et,
                             int* __restrict__ segcnt, int N, int E) {
    int e = blockIdx.x * blockDim.x + threadIdx.x;
    if (e >= E) return;
    int dst = ei[E + e];
    int r   = et[e];
    atomicAdd(&segcnt[dst * RNUM + r], 1);
}

// ---------------- scan: 3-phase over n = N*RNUM segments ----------------
__global__ __launch_bounds__(256)
void scan_part(const int* __restrict__ cnt, int* __restrict__ bsum, int n) {
    __shared__ int s[256];
    int base = blockIdx.x * 1024, t = threadIdx.x;
    int v = 0;
    for (int j = 0; j < 4; ++j) { int idx = base + j * 256 + t; if (idx < n) v += cnt[idx]; }
    s[t] = v; __syncthreads();
    for (int off = 128; off; off >>= 1) { if (t < off) s[t] += s[t + off]; __syncthreads(); }
    if (!t) bsum[blockIdx.x] = s[0];
}

__global__ __launch_bounds__(512)
void scan_top(const int* __restrict__ bsum, int* __restrict__ boff,
              int* __restrict__ segptr, int nb, int n) {
    __shared__ int s[512];
    int t = threadIdx.x;
    int v = (t < nb) ? bsum[t] : 0;
    s[t] = v;
    __syncthreads();
    for (int off = 1; off < 512; off <<= 1) {
        int y = (t >= off) ? s[t - off] : 0;
        __syncthreads();
        s[t] += y;
        __syncthreads();
    }
    if (t < nb) boff[t + 1] = s[t];
    if (!t) boff[0] = 0;
    if (t == nb - 1) segptr[n] = s[t];     // grand total = E
}

__global__ __launch_bounds__(256)
void scan_apply(const int* __restrict__ cnt, const int* __restrict__ boff,
                int* __restrict__ segptr, int* __restrict__ cursor, int n) {
    __shared__ int L[1024];
    __shared__ int SS[256];
    int base = blockIdx.x * 1024, t = threadIdx.x;
    for (int j = 0; j < 4; ++j) { int idx = base + j * 256 + t; L[j * 256 + t] = (idx < n) ? cnt[idx] : 0; }
    __syncthreads();
    int s0 = L[t*4] + L[t*4+1] + L[t*4+2] + L[t*4+3];
    SS[t] = s0; __syncthreads();
    for (int off = 1; off < 256; off <<= 1) {
        int y = (t >= off) ? SS[t - off] : 0;
        __syncthreads();
        SS[t] += y;
        __syncthreads();
    }
    int e0 = (t ? SS[t - 1] : 0) + boff[blockIdx.x];
    int4 ov;
    int a;
    a = L[t*4+0]; ov.x = e0; e0 += a;
    a = L[t*4+1]; ov.y = e0; e0 += a;
    a = L[t*4+2]; ov.z = e0; e0 += a;
    a = L[t*4+3]; ov.w = e0; e0 += a;
    int idx0 = base + t * 4;
    if (idx0 + 3 < n) {
        *(int4*)(segptr + idx0) = ov;
        *(int4*)(cursor + idx0) = ov;
    } else {
        int vals[4] = {ov.x, ov.y, ov.z, ov.w};
        for (int k = 0; k < 4; ++k)
            if (idx0 + k < n) { segptr[idx0 + k] = vals[k]; cursor[idx0 + k] = vals[k]; }
    }
}

// ---------------- K3: scatter edges into composite CSR ----------------
__global__ void scatter_kernel(const int* __restrict__ ei, const int* __restrict__ et,
                               int* __restrict__ cursor, unsigned* __restrict__ esrc,
                               int N, int E) {
    int e = blockIdx.x * blockDim.x + threadIdx.x;
    if (e >= E) return;
    int src = ei[e];
    int dst = ei[E + e];
    int r   = et[e];
    int pos = atomicAdd(&cursor[dst * RNUM + r], 1);
    esrc[pos] = (unsigned)src;
}

// ---------------- prep: xhalf + wconv_rgcn + wconv_qkvs fused ----------------
__global__ __launch_bounds__(256)
void prep_kernel(const float* __restrict__ x, us* __restrict__ xh,
                 const float* __restrict__ Wrel, const float* __restrict__ Wroot,
                 ushort4* __restrict__ Btr,
                 const float* __restrict__ Wq, const float* __restrict__ Wk,
                 const float* __restrict__ Wv, const float* __restrict__ Ws,
                 ushort4* __restrict__ Btq, int xblocks) {
    int b = blockIdx.x;
    if (b < xblocks) {
        int i = b * 256 + threadIdx.x;             // i < N*G/8 exactly
        float4 a = ((const float4*)x)[2*i];
        float4 c = ((const float4*)x)[2*i+1];
        ushort4 u0 = { f2h(a.x), f2h(a.y), f2h(a.z), f2h(a.w) };
        ushort4 u1 = { f2h(c.x), f2h(c.y), f2h(c.z), f2h(c.w) };
        ((ushort4*)xh)[2*i]   = u0;
        ((ushort4*)xh)[2*i+1] = u1;
    } else if (b < xblocks + 112) {
        int idx = (b - xblocks) * 256 + threadIdx.x;   // < 224*128 exactly
        int kq = idx >> 7, n = idx & 127;
        ushort4 o;
        us* op = (us*)&o;
#pragma unroll
        for (int i = 0; i < 4; ++i) {
            int k = 4 * kq + i;
            float v = (k < 768) ? Wrel[(size_t)k * 128 + n] : Wroot[(size_t)(k - 768) * 128 + n];
            op[i] = f2h(v);
        }
        Btr[idx] = o;
    } else {
        int idx = (b - xblocks - 112) * 256 + threadIdx.x;  // < 32*512 exactly
        int kq = idx >> 9, n = idx & 511;
        int quad = n >> 7, nl = n & 127;
        const float* W = (quad == 0) ? Wq : (quad == 1) ? Wk : (quad == 2) ? Wv : Ws;
        ushort4 o;
        us* op = (us*)&o;
#pragma unroll
        for (int i = 0; i < 4; ++i) {
            int k = 4 * kq + i;
            op[i] = f2h(W[(size_t)k * 128 + nl]);
        }
        Btq[idx] = o;
    }
}

// ---------------- K4: aggregation (wave/node, 8-deep gathers, scalar rel-flush) ----------------
// Row-major coalesced output: meanh[i][r*128 + d], wave writes 256B contiguous per flush.
__global__ __launch_bounds__(256)
void agg_kernel(const us* __restrict__ xh, const int* __restrict__ segptr,
                const unsigned* __restrict__ esrc, us* __restrict__ meanh, int N) {
    const int wv = threadIdx.x >> 6, l = threadIdx.x & 63;
    const int i = blockIdx.x * 4 + wv;
    if (i >= N) return;
    const int e0 = __builtin_amdgcn_readfirstlane(segptr[i * RNUM]);
    const int e1 = __builtin_amdgcn_readfirstlane(segptr[i * RNUM + RNUM]);

    int rcur = 0;
    int sstart = e0;
    int bnext = __builtin_amdgcn_readfirstlane(segptr[i * RNUM + 1]);
    float2 a = {0.f, 0.f};
    us* wbase = meanh + (size_t)i * 768 + 2 * l;

#define FLUSH() { \
    float sc_ = 1.f / fmaxf((float)(bnext - sstart), 1.f); \
    ushort2 t2_ = { f2h(a.x * sc_), f2h(a.y * sc_) }; \
    *(ushort2*)(wbase + rcur * 128) = t2_; \
    a.x = 0.f; a.y = 0.f; \
    sstart = bnext; ++rcur; \
    if (rcur < RNUM) bnext = __builtin_amdgcn_readfirstlane(segptr[i * RNUM + rcur + 1]); }

#define GET(J) ((unsigned)__shfl((int)pv, (J)))
#define LX(Q)  (*(const ushort2*)(xh + (size_t)(Q) * G + 2 * l))
#define STEP(U) { while (p >= bnext && rcur < RNUM - 1) FLUSH(); \
                  a.x += h2f((U).x); a.y += h2f((U).y); ++p; }

    int p = e0;
    for (int wb = e0; wb < e1; wb += 64) {
        const int nc = min(64, e1 - wb);
        unsigned pv = (wb + l < e1) ? esrc[wb + l] : 0u;
        int j = 0;
        while (j + 8 <= nc) {
            unsigned q0 = GET(j+0), q1 = GET(j+1), q2 = GET(j+2), q3 = GET(j+3);
            unsigned q4 = GET(j+4), q5 = GET(j+5), q6 = GET(j+6), q7 = GET(j+7);
            ushort2 u0 = LX(q0), u1 = LX(q1), u2 = LX(q2), u3 = LX(q3);
            ushort2 u4 = LX(q4), u5 = LX(q5), u6 = LX(q6), u7 = LX(q7);
            STEP(u0); STEP(u1); STEP(u2); STEP(u3);
            STEP(u4); STEP(u5); STEP(u6); STEP(u7);
            j += 8;
        }
        while (j + 2 <= nc) {
            unsigned q0 = GET(j), q1 = GET(j+1);
            ushort2 u0 = LX(q0), u1 = LX(q1);
            STEP(u0); STEP(u1);
            j += 2;
        }
        if (j < nc) {
            unsigned q0 = GET(j);
            ushort2 u0 = LX(q0);
            STEP(u0);
            ++j;
        }
    }
    while (rcur < RNUM) FLUSH();
#undef STEP
#undef LX
#undef GET
#undef FLUSH
}

// ---------------- K5: RGCN GEMM via MFMA — row-major A reads, B-register reuse ----------------
// 256 thr / 4 waves; wave owns 32 rows (2 x 16-row A-frag tiles); block = 128 rows.
// A-frag k-mapping is contiguous: af.u[0] = row[k = 32s + 4lh .. +3], af.u[1] = +16.
__global__ __launch_bounds__(256)
void rgcn_mfma4(const us* __restrict__ xh, const us* __restrict__ meanh,
                const ushort4* __restrict__ Btr, const float* __restrict__ brg,
                us* __restrict__ xrh, int N) {
    const int tid = threadIdx.x;
    const int w = tid >> 6, l = tid & 63;
    const int lh = l >> 4, lm = l & 15;
    const int rowbase = blockIdx.x * 128 + w * 32;

    const us* am[2];
    const us* ar[2];
#pragma unroll
    for (int tt = 0; tt < 2; ++tt) {
        int gr = min(rowbase + tt * 16 + lm, N - 1);
        am[tt] = meanh + (size_t)gr * 768;
        ar[tt] = xh + (size_t)gr * 128;
    }

    f32x4 acc[2][8];
#pragma unroll
    for (int tt = 0; tt < 2; ++tt)
#pragma unroll
        for (int ct = 0; ct < 8; ++ct) {
            float b = brg[ct * 16 + lm];
            acc[tt][ct] = (f32x4){b, b, b, b};
        }

    // means part: k-blocks s = 0..23 (6 relations x 128 dims, row-major)
    for (int s = 0; s < 24; ++s) {
        const int kqg = s * 8 + lh;
        const ushort4* B0 = Btr + (size_t)kqg * 128 + lm;
        const ushort4* B1 = B0 + 4 * 128;
        FragU bf[8];
#pragma unroll
        for (int ct = 0; ct < 8; ++ct) { bf[ct].u[0] = B0[ct * 16]; bf[ct].u[1] = B1[ct * 16]; }
#pragma unroll
        for (int tt = 0; tt < 2; ++tt) {
            FragU af;
            af.u[0] = *(const ushort4*)(am[tt] + s * 32 + 4 * lh);
            af.u[1] = *(const ushort4*)(am[tt] + s * 32 + 4 * lh + 16);
#pragma unroll
            for (int ct = 0; ct < 8; ++ct)
                acc[tt][ct] = __builtin_amdgcn_mfma_f32_16x16x32_f16(af.v, bf[ct].v, acc[tt][ct], 0, 0, 0);
        }
    }
    // root part: k-blocks s = 0..3 from xh
#pragma unroll
    for (int s = 0; s < 4; ++s) {
        const int kqg = 192 + s * 8 + lh;
        const ushort4* B0 = Btr + (size_t)kqg * 128 + lm;
        const ushort4* B1 = B0 + 4 * 128;
        FragU bf[8];
#pragma unroll
        for (int ct = 0; ct < 8; ++ct) { bf[ct].u[0] = B0[ct * 16]; bf[ct].u[1] = B1[ct * 16]; }
#pragma unroll
        for (int tt = 0; tt < 2; ++tt) {
            FragU af;
            af.u[0] = *(const ushort4*)(ar[tt] + s * 32 + 4 * lh);
            af.u[1] = *(const ushort4*)(ar[tt] + s * 32 + 4 * lh + 16);
#pragma unroll
            for (int ct = 0; ct < 8; ++ct)
                acc[tt][ct] = __builtin_amdgcn_mfma_f32_16x16x32_f16(af.v, bf[ct].v, acc[tt][ct], 0, 0, 0);
        }
    }

#pragma unroll
    for (int tt = 0; tt < 2; ++tt)
#pragma unroll
        for (int ct = 0; ct < 8; ++ct)
#pragma unroll
            for (int i = 0; i < 4; ++i) {
                int r = rowbase + tt * 16 + 4 * lh + i;
                if (r < N) xrh[(size_t)r * 128 + ct * 16 + lm] = f2h(acc[tt][ct][i]);
            }
}

// ---------------- K6: q|k|v|skip via MFMA, all-fp16 outputs ----------------
__global__ __launch_bounds__(256)
void qkvs_mfma3(const us* __restrict__ xrh, const ushort4* __restrict__ Btq,
                const float* __restrict__ bq, const float* __restrict__ bk,
                const float* __restrict__ bv, const float* __restrict__ bs,
                us* __restrict__ qsh, us* __restrict__ kvh, int N) {
    const int tid = threadIdx.x;
    const int quad = tid >> 6, l = tid & 63;
    const int lh = l >> 4, lm = l & 15;
    const int base = blockIdx.x * 32;
    const float* bias = (quad == 0) ? bq : (quad == 1) ? bk : (quad == 2) ? bv : bs;

    const us* ap[2];
#pragma unroll
    for (int tt = 0; tt < 2; ++tt) {
        int ar = min(base + tt * 16 + lm, N - 1);
        ap[tt] = xrh + (size_t)ar * 128;
    }

    f32x4 acc[2][8];
#pragma unroll
    for (int tt = 0; tt < 2; ++tt)
#pragma unroll
        for (int ct = 0; ct < 8; ++ct) {
            float b = bias[ct * 16 + lm];
            acc[tt][ct] = (f32x4){b, b, b, b};
        }

#pragma unroll
    for (int s = 0; s < 4; ++s) {
        const int kq = s * 8 + lh;
        const ushort4* B0 = Btq + (size_t)kq * 512 + quad * 128 + lm;
        const ushort4* B1 = B0 + 4 * 512;
        FragU bf[8];
#pragma unroll
        for (int ct = 0; ct < 8; ++ct) { bf[ct].u[0] = B0[ct * 16]; bf[ct].u[1] = B1[ct * 16]; }
#pragma unroll
        for (int tt = 0; tt < 2; ++tt) {
            FragU af;
            af.u[0] = *(const ushort4*)(ap[tt] + kq * 4);
            af.u[1] = *(const ushort4*)(ap[tt] + kq * 4 + 16);
#pragma unroll
            for (int ct = 0; ct < 8; ++ct)
                acc[tt][ct] = __builtin_amdgcn_mfma_f32_16x16x32_f16(af.v, bf[ct].v, acc[tt][ct], 0, 0, 0);
        }
    }

    if (quad == 0 || quad == 3) {
        const int off = (quad == 0) ? 0 : 128;
#pragma unroll
        for (int tt = 0; tt < 2; ++tt)
#pragma unroll
            for (int ct = 0; ct < 8; ++ct)
#pragma unroll
                for (int i = 0; i < 4; ++i) {
                    int r = base + tt * 16 + 4 * lh + i;
                    if (r < N) qsh[(size_t)r * 256 + off + ct * 16 + lm] = f2h(acc[tt][ct][i]);
                }
    } else {
        const int off = (quad == 1) ? 0 : 2;
#pragma unroll
        for (int tt = 0; tt < 2; ++tt)
#pragma unroll
            for (int ct = 0; ct < 8; ++ct)
#pragma unroll
                for (int i = 0; i < 4; ++i) {
                    int r = base + tt * 16 + 4 * lh + i;
                    int col = ct * 16 + lm;
                    if (r < N) kvh[(size_t)r * 256 + (col >> 1) * 4 + (col & 1) + off] = f2h(acc[tt][ct][i]);
                }
    }
}

// ---------------- K7: attention — 32 lanes/node, 2 nodes/wave, 8-deep online softmax + BN ----------------
__global__ __launch_bounds__(256)
void attn_kernel(const us* __restrict__ qsh, const us* __restrict__ kvh,
                 const int* __restrict__ segptr, const unsigned* __restrict__ esrc,
                 float* __restrict__ out, float* __restrict__ bnS,
                 float* __restrict__ bnQ, int N) {
    __shared__ float sS[128], sQ[128];
    const int tid = threadIdx.x;
    if (tid < 128) { sS[tid] = 0.f; sQ[tid] = 0.f; }
    __syncthreads();

    const int wv = tid >> 6, l = tid & 63;
    const int hh = l >> 5, ll = l & 31;
    const int stride = gridDim.x * 8;
    const float QS = 0.17677669529663687f;   // 1/sqrt(32)
    float4 bsum = {0,0,0,0}, bsq = {0,0,0,0};

#define SCORE(D, S) { \
    float2 ka_ = h22((D).x), kb_ = h22((D).z); \
    float t_ = q4.x*ka_.x + q4.y*ka_.y + q4.z*kb_.x + q4.w*kb_.y; \
    t_ += __shfl_xor(t_, 1, 8); t_ += __shfl_xor(t_, 2, 8); t_ += __shfl_xor(t_, 4, 8); \
    S = t_; }

    for (int ibase = blockIdx.x * 8 + wv * 2; ibase < N; ibase += stride) {
        const bool act = (ibase + hh) < N;
        const int i = min(ibase + hh, N - 1);

        int2 qu = *(const int2*)(qsh + (size_t)i * 256 + 4 * ll);
        float2 qa = h22(qu.x), qb = h22(qu.y);
        float4 q4 = { qa.x * QS, qa.y * QS, qb.x * QS, qb.y * QS };

        float m = -INFINITY, den = 0.f;
        float4 acc = {0,0,0,0};
        const int e0 = segptr[(size_t)i * RNUM], e1 = segptr[(size_t)i * RNUM + RNUM];

        for (int wb = e0; wb < e1; wb += 32) {
            const int nc = min(32, e1 - wb);
            unsigned pv = (wb + ll < e1) ? esrc[wb + ll] : 0u;
            int j = 0;
            for (; j + 8 <= nc; j += 8) {
                unsigned p0 = (unsigned)__shfl((int)pv, j+0, 32);
                unsigned p1 = (unsigned)__shfl((int)pv, j+1, 32);
                unsigned p2 = (unsigned)__shfl((int)pv, j+2, 32);
                unsigned p3 = (unsigned)__shfl((int)pv, j+3, 32);
                unsigned p4 = (unsigned)__shfl((int)pv, j+4, 32);
                unsigned p5 = (unsigned)__shfl((int)pv, j+5, 32);
                unsigned p6 = (unsigned)__shfl((int)pv, j+6, 32);
                unsigned p7 = (unsigned)__shfl((int)pv, j+7, 32);
                int4 d0 = *(const int4*)(kvh + (size_t)p0 * 256 + 8 * ll);
                int4 d1 = *(const int4*)(kvh + (size_t)p1 * 256 + 8 * ll);
                int4 d2 = *(const int4*)(kvh + (size_t)p2 * 256 + 8 * ll);
                int4 d3 = *(const int4*)(kvh + (size_t)p3 * 256 + 8 * ll);
                int4 d4 = *(const int4*)(kvh + (size_t)p4 * 256 + 8 * ll);
                int4 d5 = *(const int4*)(kvh + (size_t)p5 * 256 + 8 * ll);
                int4 d6 = *(const int4*)(kvh + (size_t)p6 * 256 + 8 * ll);
                int4 d7 = *(const int4*)(kvh + (size_t)p7 * 256 + 8 * ll);
                float s0, s1, s2, s3, s4, s5, s6, s7;
                SCORE(d0, s0); SCORE(d1, s1); SCORE(d2, s2); SCORE(d3, s3);
                SCORE(d4, s4); SCORE(d5, s5); SCORE(d6, s6); SCORE(d7, s7);
                float mx = fmaxf(m, fmaxf(
                    fmaxf(fmaxf(s0, s1), fmaxf(s2, s3)),
                    fmaxf(fmaxf(s4, s5), fmaxf(s6, s7))));
                float rs = __expf(m - mx);
                float w0 = __expf(s0 - mx), w1 = __expf(s1 - mx);
                float w2 = __expf(s2 - mx), w3 = __expf(s3 - mx);
                float w4 = __expf(s4 - mx), w5 = __expf(s5 - mx);
                float w6 = __expf(s6 - mx), w7 = __expf(s7 - mx);
                den = den * rs + (((w0 + w1) + (w2 + w3)) + ((w4 + w5) + (w6 + w7)));
                float2 va0 = h22(d0.y), vb0 = h22(d0.w);
                float2 va1 = h22(d1.y), vb1 = h22(d1.w);
                float2 va2 = h22(d2.y), vb2 = h22(d2.w);
                float2 va3 = h22(d3.y), vb3 = h22(d3.w);
                float2 va4 = h22(d4.y), vb4 = h22(d4.w);
                float2 va5 = h22(d5.y), vb5 = h22(d5.w);
                float2 va6 = h22(d6.y), vb6 = h22(d6.w);
                float2 va7 = h22(d7.y), vb7 = h22(d7.w);
                acc.x = acc.x * rs + ((w0*va0.x + w1*va1.x) + (w2*va2.x + w3*va3.x))
                                   + ((w4*va4.x + w5*va5.x) + (w6*va6.x + w7*va7.x));
                acc.y = acc.y * rs + ((w0*va0.y + w1*va1.y) + (w2*va2.y + w3*va3.y))
                                   + ((w4*va4.y + w5*va5.y) + (w6*va6.y + w7*va7.y));
                acc.z = acc.z * rs + ((w0*vb0.x + w1*vb1.x) + (w2*vb2.x + w3*vb3.x))
                                   + ((w4*vb4.x + w5*vb5.x) + (w6*vb6.x + w7*vb7.x));
                acc.w = acc.w * rs + ((w0*vb0.y + w1*vb1.y) + (w2*vb2.y + w3*vb3.y))
                                   + ((w4*vb4.y + w5*vb5.y) + (w6*vb6.y + w7*vb7.y));
                m = mx;
            }
            for (; j + 4 <= nc; j += 4) {
                unsigned p0 = (unsigned)__shfl((int)pv, j+0, 32);
                unsigned p1 = (unsigned)__shfl((int)pv, j+1, 32);
                unsigned p2 = (unsigned)__shfl((int)pv, j+2, 32);
                unsigned p3 = (unsigned)__shfl((int)pv, j+3, 32);
                int4 d0 = *(const int4*)(kvh + (size_t)p0 * 256 + 8 * ll);
                int4 d1 = *(const int4*)(kvh + (size_t)p1 * 256 + 8 * ll);
                int4 d2 = *(const int4*)(kvh + (size_t)p2 * 256 + 8 * ll);
                int4 d3 = *(const int4*)(kvh + (size_t)p3 * 256 + 8 * ll);
                float s0, s1, s2, s3;
                SCORE(d0, s0); SCORE(d1, s1); SCORE(d2, s2); SCORE(d3, s3);
                float mx = fmaxf(m, fmaxf(fmaxf(s0, s1), fmaxf(s2, s3)));
                float rs = __expf(m - mx);
                float w0 = __expf(s0 - mx), w1 = __expf(s1 - mx);
                float w2 = __expf(s2 - mx), w3 = __expf(s3 - mx);
                den = den * rs + ((w0 + w1) + (w2 + w3));
                float2 va0 = h22(d0.y), vb0 = h22(d0.w);
                float2 va1 = h22(d1.y), vb1 = h22(d1.w);
                float2 va2 = h22(d2.y), vb2 = h22(d2.w);
                float2 va3 = h22(d3.y), vb3 = h22(d3.w);
                acc.x = acc.x * rs + w0*va0.x + w1*va1.x + w2*va2.x + w3*va3.x;
                acc.y = acc.y * rs + w0*va0.y + w1*va1.y + w2*va2.y + w3*va3.y;
                acc.z = acc.z * rs + w0*vb0.x + w1*vb1.x + w2*vb2.x + w3*vb3.x;
                acc.w = acc.w * rs + w0*vb0.y + w1*vb1.y + w2*vb2.y + w3*vb3.y;
                m = mx;
            }
            for (; j < nc; ++j) {
                unsigned p0 = (unsigned)__shfl((int)pv, j, 32);
                int4 d0 = *(const int4*)(kvh + (size_t)p0 * 256 + 8 * ll);
                float s0; SCORE(d0, s0);
                float mx = fmaxf(m, s0);
                float rs = __expf(m - mx);
                float w0 = __expf(s0 - mx);
                den = den * rs + w0;
                float2 va0 = h22(d0.y), vb0 = h22(d0.w);
                acc.x = acc.x * rs + w0 * va0.x;
                acc.y = acc.y * rs + w0 * va0.y;
                acc.z = acc.z * rs + w0 * vb0.x;
                acc.w = acc.w * rs + w0 * vb0.y;
                m = mx;
            }
        }

        float inv = 1.f / (den + 1e-16f);
        int2 su = *(const int2*)(qsh + (size_t)i * 256 + 128 + 4 * ll);
        float2 sa = h22(su.x), sb = h22(su.y);
        float4 o = { acc.x * inv + sa.x, acc.y * inv + sa.y,
                     acc.z * inv + sb.x, acc.w * inv + sb.y };
        if (act) {
            *(float4*)(out + (size_t)i * OUTW + 4 * ll) = o;
            bsum.x += o.x; bsum.y += o.y; bsum.z += o.z; bsum.w += o.w;
            bsq.x += o.x*o.x; bsq.y += o.y*o.y; bsq.z += o.z*o.z; bsq.w += o.w*o.w;
        }
    }
#undef SCORE

    atomicAdd(&sS[4*ll + 0], bsum.x);
    atomicAdd(&sS[4*ll + 1], bsum.y);
    atomicAdd(&sS[4*ll + 2], bsum.z);
    atomicAdd(&sS[4*ll + 3], bsum.w);
    atomicAdd(&sQ[4*ll + 0], bsq.x);
    atomicAdd(&sQ[4*ll + 1], bsq.y);
    atomicAdd(&sQ[4*ll + 2], bsq.z);
    atomicAdd(&sQ[4*ll + 3], bsq.w);
    __syncthreads();
    if (tid < 128) {
        atomicAdd(&bnS[tid], sS[tid]);
        atomicAdd(&bnQ[tid], sQ[tid]);
    }
}

// ---------------- K8: BN stats (inline) + apply + LeakyReLU ----------------
__global__ __launch_bounds__(256)
void apply_kernel(float* __restrict__ out, const float* __restrict__ bnS,
                  const float* __restrict__ bnQ, const float* __restrict__ gamma,
                  const float* __restrict__ beta, int N, int total4) {
    __shared__ float A_s[128], B_s[128];
    const int tid = threadIdx.x;
    if (tid < 128) {
        float fN  = (float)N;
        float mu  = bnS[tid] / fN;
        float var = bnQ[tid] / fN - mu * mu;
        float rv  = rsqrtf(var + 1e-5f);
        float A   = rv * gamma[tid];
        A_s[tid] = A;
        B_s[tid] = beta[tid] - mu * A;
    }
    __syncthreads();
    for (int idx4 = blockIdx.x * 256 + tid; idx4 < total4; idx4 += gridDim.x * 256) {
        float4 v = ((const float4*)out)[idx4];
        int c0 = (idx4 * 4) & 127;
        float y;
        y = A_s[c0    ] * v.x + B_s[c0    ]; v.x = (y > 0.f) ? y : 0.01f * y;
        y = A_s[c0 + 1] * v.y + B_s[c0 + 1]; v.y = (y > 0.f) ? y : 0.01f * y;
        y = A_s[c0 + 2] * v.z + B_s[c0 + 2]; v.z = (y > 0.f) ? y : 0.01f * y;
        y = A_s[c0 + 3] * v.w + B_s[c0 + 3]; v.w = (y > 0.f) ? y : 0.01f * y;
        ((float4*)out)[idx4] = v;
    }
}

// ---------------- launch ----------------
static inline char* alignp(char* p) {
    return (char*)(((uintptr_t)p + 255) & ~(uintptr_t)255);
}

extern "C" void kernel_launch(void* const* d_in, const int* in_sizes, int n_in,
                              void* d_out, int out_size, void* d_ws, size_t ws_size,
                              hipStream_t stream) {
    const float* x     = (const float*)d_in[0];
    const int*   ei    = (const int*)  d_in[2];
    const int*   et    = (const int*)  d_in[3];
    const float* Wrel  = (const float*)d_in[4];
    const float* Wroot = (const float*)d_in[5];
    const float* brg   = (const float*)d_in[6];
    const float* Wq    = (const float*)d_in[7];
    const float* bq    = (const float*)d_in[8];
    const float* Wk    = (const float*)d_in[9];
    const float* bk    = (const float*)d_in[10];
    const float* Wv    = (const float*)d_in[11];
    const float* bv    = (const float*)d_in[12];
    const float* Wsk   = (const float*)d_in[13];
    const float* bsk   = (const float*)d_in[14];
    const float* gamma = (const float*)d_in[15];
    const float* beta  = (const float*)d_in[16];
    float* out = (float*)d_out;

    const int N = in_sizes[0] / G;
    const int E = in_sizes[3];
    const int NSEG = N * RNUM;
    const int NB_SCAN = (NSEG + 1023) / 1024;   // <= 512

    // ---- workspace carve ----
    char* w = (char*)d_ws;
    int* segcnt = (int*)w;           w += (size_t)NSEG * 4;
    float* bnS = (float*)w;          w += 128 * 4;
    float* bnQ = (float*)w;          w += 128 * 4;
    size_t zero_bytes = (size_t)(w - (char*)d_ws);
    w = alignp(w);
    int* bsum  = (int*)w;            w += 512 * 4;
    int* boff  = (int*)w;            w += 513 * 4;
    w = alignp(w);
    int* segptr = (int*)w;           w += (size_t)(NSEG + 1) * 4;
    w = alignp(w);
    int* cursor = (int*)w;           w += (size_t)NSEG * 4;
    w = alignp(w);
    unsigned* esrc = (unsigned*)w;   w += (size_t)E * 4;
    w = alignp(w);
    us* xh     = (us*)w;             w += (size_t)N * G * 2;
    w = alignp(w);
    us* xrh    = (us*)w;             w += (size_t)N * OUTW * 2;
    w = alignp(w);
    ushort4* Btr = (ushort4*)w;      w += (size_t)224 * 128 * 8;
    w = alignp(w);
    ushort4* Btq = (ushort4*)w;      w += (size_t)32 * 512 * 8;
    w = alignp(w);
    // aliased region: meanh [N][768] fp16 row-major (76.8MB);
    // later qsh [N][256] fp16 (25.6MB) + kvh [N][256] fp16 (25.6MB)
    us* meanh = (us*)w;
    us* qsh   = (us*)w;
    us* kvh   = (us*)(w + (size_t)N * 256 * 2);

    hipMemsetAsync(d_ws, 0, zero_bytes, stream);

    int eb = (E + 255) / 256;
    count_kernel<<<eb, 256, 0, stream>>>(ei, et, segcnt, N, E);

    scan_part<<<NB_SCAN, 256, 0, stream>>>(segcnt, bsum, NSEG);
    scan_top<<<1, 512, 0, stream>>>(bsum, boff, segptr, NB_SCAN, NSEG);
    scan_apply<<<NB_SCAN, 256, 0, stream>>>(segcnt, boff, segptr, cursor, NSEG);

    scatter_kernel<<<eb, 256, 0, stream>>>(ei, et, cursor, esrc, N, E);

    int xblocks = N * G / 8 / 256;               // 3125
    prep_kernel<<<xblocks + 112 + 64, 256, 0, stream>>>(x, xh, Wrel, Wroot, Btr,
                                                        Wq, Wk, Wv, Wsk, Btq, xblocks);

    agg_kernel<<<(N + 3) / 4, 256, 0, stream>>>(xh, segptr, esrc, meanh, N);

    rgcn_mfma4<<<(N + 127) / 128, 256, 0, stream>>>(xh, meanh, Btr, brg, xrh, N);

    qkvs_mfma3<<<(N + 31) / 32, 256, 0, stream>>>(xrh, Btq, bq, bk, bv, bsk, qsh, kvh, N);

    attn_kernel<<<2048, 256, 0, stream>>>(qsh, kvh, segptr, esrc, out, bnS, bnQ, N);

    int total4 = N * OUTW / 4;
    apply_kernel<<<2048, 256, 0, stream>>>(out, bnS, bnQ, gamma, beta, N, total4);
}